// Round 4
// baseline (882.438 us; speedup 1.0000x reference)
//
#include <hip/hip_runtime.h>

#define BB   8192
#define LEN  40
#define LDN  12
#define PQN  237
#define INN  256
#define HN   64
#define BT   32                 // encoder batches per block (2 MFMA n-tiles)
#define ENC_BLOCKS (BB / BT)    // 256 -> 1 block/CU
#define DW   8                  // decoder batches per block (1 wave each)
#define DEC_BLOCKS (BB / DW)    // 1024
#define XPS  256                // xpre row stride in f16 (power of 2)

typedef unsigned int  u32;
typedef _Float16 f16;
typedef f16  half8 __attribute__((ext_vector_type(8)));
typedef f16  f16x4 __attribute__((ext_vector_type(4)));
typedef float f32x4 __attribute__((ext_vector_type(4)));

#define XS 264   // X/P LDS row stride (f16): reads 2-way max bank aliasing
#define HS 72    // U/H/C LDS row stride (f16): 2-way max

// weight offsets (f16 elements) in converted buffer
#define OFF_WI   0
#define OFF_WE   16384
#define OFF_VD   24576
#define OFF_WIH  40960
#define OFF_WHH  106496
#define OFF_WD   122880
#define W_TOTAL  126976

// LDS-staged embedding tables (f32) for fallback encoder
#define T_H   0
#define T_W   120
#define T_M   144
#define T_Y   196
#define T_TOT 574

#define PREP_BLOCKS (BB * LEN / 32)          // 10240
#define CONV_BLOCKS ((W_TOTAL + 255) / 256)  // 496

__device__ __forceinline__ float rcp_(float x){
#if __has_builtin(__builtin_amdgcn_rcpf)
  return __builtin_amdgcn_rcpf(x);
#else
  return 1.0f / x;
#endif
}
__device__ __forceinline__ float sigm(float x){
  return rcp_(1.0f + exp2f(-1.44269504f * x));
}
// tanh = 1 - 2/(e^{2x}+1); exp2 over/underflow saturates cleanly, no clamp.
__device__ __forceinline__ float tanhf_(float x){
  float e = exp2f(2.88539008f * x);
  return 1.0f - 2.0f * rcp_(e + 1.0f);
}

// lgkm-only barrier: LDS producer->consumer ordering WITHOUT draining vmcnt.
__device__ __forceinline__ void bar_lds(){
  asm volatile("s_waitcnt lgkmcnt(0)" ::: "memory");
  __builtin_amdgcn_s_barrier();
  asm volatile("" ::: "memory");
}

// ---------------- weight f32 -> f16 conversion (fallback path) -------------
__global__ __launch_bounds__(256) void conv_w(
    const float* __restrict__ Wi, const float* __restrict__ We,
    const float* __restrict__ Vd, const float* __restrict__ Wih,
    const float* __restrict__ Whh, const float* __restrict__ Wd,
    f16* __restrict__ dst)
{
  int i = blockIdx.x * 256 + threadIdx.x;
  if (i >= W_TOTAL) return;
  float v;
  if      (i < OFF_WE)  v = Wi [i - OFF_WI ];
  else if (i < OFF_VD)  v = We [i - OFF_WE ];
  else if (i < OFF_WIH) v = Vd [i - OFF_VD ];
  else if (i < OFF_WHH) v = Wih[i - OFF_WIH];
  else if (i < OFF_WD)  v = Whh[i - OFF_WHH];
  else                  v = Wd [i - OFF_WD ];
  dst[i] = (f16)v;
}

// ---------------- prep_all: X materialization + fused weight convert -------
__global__ __launch_bounds__(256) void prep_all(
    const float* __restrict__ ipq,
    const float* __restrict__ e_h, const float* __restrict__ e_w,
    const float* __restrict__ e_m, const float* __restrict__ e_y,
    const int*  __restrict__ itime,
    f16* __restrict__ xpre,
    const float* __restrict__ Wi, const float* __restrict__ We,
    const float* __restrict__ Vd, const float* __restrict__ Wih,
    const float* __restrict__ Whh, const float* __restrict__ Wd,
    f16* __restrict__ wdst)
{
  if (blockIdx.x >= PREP_BLOCKS) {
    int i = (blockIdx.x - PREP_BLOCKS) * 256 + threadIdx.x;
    if (i >= W_TOTAL) return;
    float v;
    if      (i < OFF_WE)  v = Wi [i - OFF_WI ];
    else if (i < OFF_VD)  v = We [i - OFF_WE ];
    else if (i < OFF_WIH) v = Vd [i - OFF_VD ];
    else if (i < OFF_WHH) v = Wih[i - OFF_WIH];
    else if (i < OFF_WD)  v = Whh[i - OFF_WHH];
    else                  v = Wd [i - OFF_WD ];
    wdst[i] = (f16)v;
    return;
  }
  const int wv = threadIdx.x >> 6, l = threadIdx.x & 63;
  const size_t row0 = (size_t)blockIdx.x * 32 + (size_t)wv * 8;
  int4 itv[8];
  #pragma unroll
  for (int r = 0; r < 8; ++r)
    itv[r] = *(const int4*)(itime + (row0 + r) * 4);
  #pragma unroll
  for (int r = 0; r < 8; ++r) {
    const size_t row = row0 + r;               // = b*LEN + t
    const float* src = ipq + row * PQN;
    f16* dst = xpre + row * XPS;
    #pragma unroll
    for (int k = 0; k < 3; ++k) {
      const int c = k * 64 + l;
      dst[c] = (f16)src[c];
    }
    {
      const int c = 192 + l;
      float v;
      if (c < PQN) v = src[c];
      else {
        const int o = c - PQN;
        if      (o < 5 ) v = e_h[itv[r].x * 5 + o];
        else if (o < 8 ) v = e_w[itv[r].y * 3 + (o - 5)];
        else if (o < 12) v = e_m[itv[r].z * 4 + (o - 8)];
        else             v = e_y[itv[r].w * 7 + (o - 12)];
      }
      dst[c] = (f16)v;
    }
  }
}

// ---------------- encoder v4: 8 waves (2/SIMD), weights reg+LDS split ------
// Wave w = (wsub = w&3, bt = w>>2): handles n-tile bt, gate tiles wsub+4i.
// Registers: wif[8] (Wi slice, 32) + whf[4][8] (Wih slices, 128).
// LDS: We/Vd/Whh/Wd fragments at [tile][kt][lane] (lane-contiguous b128
// reads, conflict-free) + Vd/eb biases.  __launch_bounds__(512,2) caps
// regs at 256/wave -> 2 waves/SIMD resident.
__global__ __launch_bounds__(512, 2) void enc_x(
    const f16* __restrict__ xpre,
    const float* __restrict__ Wi_b,   // (64)
    const float* __restrict__ Vd_b,   // (256)
    const float* __restrict__ ebih, const float* __restrict__ ebhh, // (256)
    const float* __restrict__ Wd_b,   // (64)
    const f16*  __restrict__ wAll,
    f16* __restrict__ xout)           // == xpre (overlay)
{
  __shared__ __attribute__((aligned(16))) f16 Xl[2][BT * XS];
  __shared__ __attribute__((aligned(16))) f16 Ul[BT * HS];
  __shared__ __attribute__((aligned(16))) f16 Hl[2][BT * HS];
  __shared__ __attribute__((aligned(16))) f16 Cl[2][BT * HS];
  __shared__ __attribute__((aligned(16))) f16 Wml[BT * HS];
  __shared__ float Sred[2 * 64];
  __shared__ __attribute__((aligned(16))) f16 WeL[4 * 4 * 64 * 8];   // 16 KB
  __shared__ __attribute__((aligned(16))) f16 VdL[16 * 2 * 64 * 8];  // 32 KB
  __shared__ __attribute__((aligned(16))) f16 WhL[16 * 2 * 64 * 8];  // 32 KB
  __shared__ __attribute__((aligned(16))) f16 WdL[4 * 2 * 64 * 8];   //  8 KB
  __shared__ float VdbL[256];
  __shared__ float EbsL[256];

  const int tid  = threadIdx.x;
  const int w    = tid >> 6;
  const int lane = tid & 63;
  const int nl   = lane & 15;
  const int q    = lane >> 4;
  const int wsub = w & 3;
  const int bt   = w >> 2;
  const int b0   = blockIdx.x * BT;
  const int d0   = wsub * 16 + q * 4;
  const int row  = bt * 16 + nl;     // batch row (n-dim) this wave's MFMA

  // staging map (512 thr): slot j*512+tid -> row r0+16j, 16B chunk off
  const int r0  = tid >> 5;          // 0..15
  const int off = tid & 31;
  const f16* gb0 = xpre + ((size_t)(b0 + r0     ) * LEN) * XPS + off * 8;
  const f16* gb1 = xpre + ((size_t)(b0 + r0 + 16) * LEN) * XPS + off * 8;
  const u32 lwa = (u32)(r0 * XS + off * 8);
  const u32 lwb = (u32)((r0 + 16) * XS + off * 8);

  // output streaming map: one half8 per thread (32 rows x 128 cols)
  const int orow = tid >> 4;
  const int oc8  = (tid & 15) * 8;

  // ---- issue t=0 staging loads first ----
  half8 sr0 = *(const half8*)gb0;
  half8 sr1 = *(const half8*)gb1;

  // ---- register weights: Wi slice + Wih slices ----
  half8 wif[8], whf[4][8];
  {
    const f16* pw = wAll + OFF_WI + (wsub * 16 + nl) * 256 + q * 8;
    #pragma unroll
    for (int kt = 0; kt < 8; ++kt) wif[kt] = *(const half8*)(pw + kt * 32);
    #pragma unroll
    for (int i = 0; i < 4; ++i) {
      const f16* ph = wAll + OFF_WIH + ((wsub + 4*i) * 16 + nl) * 256 + q * 8;
      #pragma unroll
      for (int kt = 0; kt < 8; ++kt) whf[i][kt] = *(const half8*)(ph + kt * 32);
    }
  }
  float wib[4], wdb[4];
  #pragma unroll
  for (int r = 0; r < 4; ++r) { wib[r] = Wi_b[d0 + r]; wdb[r] = Wd_b[d0 + r]; }

  // ---- LDS weights: [tile][kt][lane] fragment layout ----
  for (int s = tid; s < 4 * 4 * 64; s += 512) {     // We: 4 tiles, kt=4
    const int tile = s >> 8, kt = (s >> 6) & 3, ln = s & 63;
    *(half8*)(&WeL[(size_t)s * 8]) = *(const half8*)(
        wAll + OFF_WE + (tile * 16 + (ln & 15)) * 128 + (ln >> 4) * 8 + kt * 32);
  }
  for (int s = tid; s < 16 * 2 * 64; s += 512) {    // Vd: 16 tiles, kt=2
    const int tile = s >> 7, kt = (s >> 6) & 1, ln = s & 63;
    *(half8*)(&VdL[(size_t)s * 8]) = *(const half8*)(
        wAll + OFF_VD + (tile * 16 + (ln & 15)) * 64 + (ln >> 4) * 8 + kt * 32);
  }
  for (int s = tid; s < 16 * 2 * 64; s += 512) {    // Whh: 16 tiles, kt=2
    const int tile = s >> 7, kt = (s >> 6) & 1, ln = s & 63;
    *(half8*)(&WhL[(size_t)s * 8]) = *(const half8*)(
        wAll + OFF_WHH + (tile * 16 + (ln & 15)) * 64 + (ln >> 4) * 8 + kt * 32);
  }
  for (int s = tid; s < 4 * 2 * 64; s += 512) {     // Wd: 4 tiles, kt=2
    const int tile = s >> 7, kt = (s >> 6) & 1, ln = s & 63;
    *(half8*)(&WdL[(size_t)s * 8]) = *(const half8*)(
        wAll + OFF_WD + (tile * 16 + (ln & 15)) * 64 + (ln >> 4) * 8 + kt * 32);
  }
  if (tid < 256) {
    VdbL[tid] = Vd_b[tid];
    EbsL[tid] = ebih[tid] + ebhh[tid];
  }
  for (int i = tid; i < BT * HS; i += 512) {
    Hl[0][i] = (f16)0.f; Cl[0][i] = (f16)0.f;
  }
  float creg[4] = {0.f, 0.f, 0.f, 0.f};
  bar_lds();

  for (int t = 0; t < LEN; ++t) {
    const int cur = t & 1, nxt = cur ^ 1;
    // ---- top: staged regs -> Xl[cur]; reissue prefetch for t+1 ----
    *(half8*)(&Xl[cur][lwa]) = sr0;
    *(half8*)(&Xl[cur][lwb]) = sr1;
    if (t + 1 < LEN) {
      sr0 = *(const half8*)(gb0 + (size_t)(t + 1) * XPS);
      sr1 = *(const half8*)(gb1 + (size_t)(t + 1) * XPS);
    }
    bar_lds();   // A: Xl[cur] + Hl[cur]/Cl[cur] (from ph4(t-1)) ready

    // ---- phase 2: U = tanh(Wi@X + We@[H;C] + b); Wml = Wd@H(t-1)+b ----
    {
      f32x4 acc = {0.f, 0.f, 0.f, 0.f};
      const f16* xb = &Xl[cur][row * XS + q * 8];
      #pragma unroll
      for (int kt = 0; kt < 8; ++kt)
        acc = __builtin_amdgcn_mfma_f32_16x16x32_f16(wif[kt], *(const half8*)(xb + kt * 32), acc, 0, 0, 0);
      const f16* hb = &Hl[cur][row * HS + q * 8];
      const f16* cb = &Cl[cur][row * HS + q * 8];
      half8 h0 = *(const half8*)hb, h1 = *(const half8*)(hb + 32);
      half8 c0 = *(const half8*)cb, c1 = *(const half8*)(cb + 32);
      acc = __builtin_amdgcn_mfma_f32_16x16x32_f16(
          *(const half8*)(&WeL[((wsub * 4 + 0) * 64 + lane) * 8]), h0, acc, 0, 0, 0);
      acc = __builtin_amdgcn_mfma_f32_16x16x32_f16(
          *(const half8*)(&WeL[((wsub * 4 + 1) * 64 + lane) * 8]), h1, acc, 0, 0, 0);
      acc = __builtin_amdgcn_mfma_f32_16x16x32_f16(
          *(const half8*)(&WeL[((wsub * 4 + 2) * 64 + lane) * 8]), c0, acc, 0, 0, 0);
      acc = __builtin_amdgcn_mfma_f32_16x16x32_f16(
          *(const half8*)(&WeL[((wsub * 4 + 3) * 64 + lane) * 8]), c1, acc, 0, 0, 0);
      f16x4 uv;
      #pragma unroll
      for (int r = 0; r < 4; ++r) uv[r] = (f16)tanhf_(acc[r] + wib[r]);
      *(f16x4*)(&Ul[row * HS + d0]) = uv;
      if (t > 0) {   // wm(t-1) -> LDS
        f32x4 aw = {0.f, 0.f, 0.f, 0.f};
        aw = __builtin_amdgcn_mfma_f32_16x16x32_f16(
            *(const half8*)(&WdL[((wsub * 2 + 0) * 64 + lane) * 8]), h0, aw, 0, 0, 0);
        aw = __builtin_amdgcn_mfma_f32_16x16x32_f16(
            *(const half8*)(&WdL[((wsub * 2 + 1) * 64 + lane) * 8]), h1, aw, 0, 0, 0);
        f16x4 wv;
        #pragma unroll
        for (int r = 0; r < 4; ++r) wv[r] = (f16)(aw[r] + wdb[r]);
        *(f16x4*)(&Wml[row * HS + d0]) = wv;
      }
    }
    bar_lds();   // B: Ul + Wml ready

    // ---- phase 3: stream outputs(t-1); ee = exp(Vd@U+b); P = X*ee ----
    if (t > 0) {
      const f16* srcp = (oc8 < 64) ? &Hl[cur][orow * HS + oc8]
                                   : &Wml[orow * HS + (oc8 - 64)];
      half8 v8 = *(const half8*)srcp;
      *(half8*)(xout + ((size_t)(b0 + orow) * LEN + (t - 1)) * XPS + oc8) = v8;
    }
    {
      const f16* ub = &Ul[row * HS + q * 8];
      half8 u0 = *(const half8*)ub, u1 = *(const half8*)(ub + 32);
      float s = 0.f;
      #pragma unroll
      for (int i = 0; i < 4; ++i) {
        const int tile = wsub + 4 * i;
        f32x4 acc = {0.f, 0.f, 0.f, 0.f};
        acc = __builtin_amdgcn_mfma_f32_16x16x32_f16(
            *(const half8*)(&VdL[((tile * 2 + 0) * 64 + lane) * 8]), u0, acc, 0, 0, 0);
        acc = __builtin_amdgcn_mfma_f32_16x16x32_f16(
            *(const half8*)(&VdL[((tile * 2 + 1) * 64 + lane) * 8]), u1, acc, 0, 0, 0);
        const int k = tile * 16 + q * 4;
        f16x4 xv = *(const f16x4*)(&Xl[cur][row * XS + k]);
        f16x4 pv;
        float ee[4];
        #pragma unroll
        for (int r = 0; r < 4; ++r) {
          ee[r] = exp2f((acc[r] + VdbL[k + r]) * 1.44269504f);
          s += ee[r];
          pv[r] = (f16)((float)xv[r] * ee[r]);
        }
        *(f16x4*)(&Xl[cur][row * XS + k]) = pv;   // unnormalized P in place
      }
      s += __shfl_xor(s, 16, 64);
      s += __shfl_xor(s, 32, 64);
      if (lane < 16) Sred[bt * 64 + wsub * 16 + lane] = s;
    }
    bar_lds();   // C: P + Sred ready

    // ---- phase 4: gates; LSTM; H/C -> next buffers (no barrier) ----
    {
      f32x4 g[4], gh[4];
      #pragma unroll
      for (int i = 0; i < 4; ++i) {
        g[i]  = (f32x4){0.f, 0.f, 0.f, 0.f};
        gh[i] = (f32x4){0.f, 0.f, 0.f, 0.f};
      }
      const f16* pb = &Xl[cur][row * XS + q * 8];
      #pragma unroll
      for (int kt = 0; kt < 8; ++kt) {
        half8 bv = *(const half8*)(pb + kt * 32);
        #pragma unroll
        for (int i = 0; i < 4; ++i)
          g[i] = __builtin_amdgcn_mfma_f32_16x16x32_f16(whf[i][kt], bv, g[i], 0, 0, 0);
      }
      const f16* hb = &Hl[cur][row * HS + q * 8];
      half8 h0 = *(const half8*)hb, h1 = *(const half8*)(hb + 32);
      #pragma unroll
      for (int i = 0; i < 4; ++i) {
        const int tile = wsub + 4 * i;
        gh[i] = __builtin_amdgcn_mfma_f32_16x16x32_f16(
            *(const half8*)(&WhL[((tile * 2 + 0) * 64 + lane) * 8]), h0, gh[i], 0, 0, 0);
        gh[i] = __builtin_amdgcn_mfma_f32_16x16x32_f16(
            *(const half8*)(&WhL[((tile * 2 + 1) * 64 + lane) * 8]), h1, gh[i], 0, 0, 0);
      }
      const float inv = rcp_(Sred[bt*64 + nl]      + Sred[bt*64 + 16 + nl]
                           + Sred[bt*64 + 32 + nl] + Sred[bt*64 + 48 + nl]);
      f16x4 hv, cv;
      #pragma unroll
      for (int r = 0; r < 4; ++r) {
        const float gi = g[0][r] * inv + gh[0][r] + EbsL[0   + d0 + r];
        const float gf = g[1][r] * inv + gh[1][r] + EbsL[64  + d0 + r];
        const float gg = g[2][r] * inv + gh[2][r] + EbsL[128 + d0 + r];
        const float go = g[3][r] * inv + gh[3][r] + EbsL[192 + d0 + r];
        float c = sigm(gf) * creg[r] + sigm(gi) * tanhf_(gg);
        creg[r] = c;
        const float h = sigm(go) * tanhf_(c);
        hv[r] = (f16)h; cv[r] = (f16)c;
      }
      *(f16x4*)(&Hl[nxt][row * HS + d0]) = hv;
      *(f16x4*)(&Cl[nxt][row * HS + d0]) = cv;
    }
    // no barrier D: next top writes Xl[nxt-array]; barrier A(t+1) orders H/C
  }

  // ---- epilogue: wm(LEN-1) + stream final outputs (H in Hl[0]) ----
  bar_lds();
  {
    const f16* hb = &Hl[0][row * HS + q * 8];
    half8 h0 = *(const half8*)hb, h1 = *(const half8*)(hb + 32);
    f32x4 aw = {0.f, 0.f, 0.f, 0.f};
    aw = __builtin_amdgcn_mfma_f32_16x16x32_f16(
        *(const half8*)(&WdL[((wsub * 2 + 0) * 64 + lane) * 8]), h0, aw, 0, 0, 0);
    aw = __builtin_amdgcn_mfma_f32_16x16x32_f16(
        *(const half8*)(&WdL[((wsub * 2 + 1) * 64 + lane) * 8]), h1, aw, 0, 0, 0);
    f16x4 wv;
    #pragma unroll
    for (int r = 0; r < 4; ++r) wv[r] = (f16)(aw[r] + wdb[r]);
    *(f16x4*)(&Wml[row * HS + d0]) = wv;
  }
  bar_lds();
  {
    const f16* srcp = (oc8 < 64) ? &Hl[0][orow * HS + oc8]
                                 : &Wml[orow * HS + (oc8 - 64)];
    half8 v8 = *(const half8*)srcp;
    *(half8*)(xout + ((size_t)(b0 + orow) * LEN + (LEN - 1)) * XPS + oc8) = v8;
  }
}

// ---------------- fallback encoder (round-2, proven): used if ws small -----
__global__ __launch_bounds__(256, 1) void enc_fb(
    const float* __restrict__ ipq,
    const float* __restrict__ e_h, const float* __restrict__ e_w,
    const float* __restrict__ e_m, const float* __restrict__ e_y,
    const float* __restrict__ Wi_b, const float* __restrict__ Vd_b,
    const float* __restrict__ ebih, const float* __restrict__ ebhh,
    const float* __restrict__ Wd_b, const f16* __restrict__ wAll,
    const int*  __restrict__ itime,
    f16* __restrict__ mid, f16* __restrict__ wmid)
{
  __shared__ __attribute__((aligned(16))) f16 Xl[BT * XS];
  __shared__ __attribute__((aligned(16))) f16 Ul[BT * HS];
  __shared__ __attribute__((aligned(16))) f16 Hl[BT * HS];
  __shared__ __attribute__((aligned(16))) f16 Cl[BT * HS];
  __shared__ float Sred[2 * 64];
  __shared__ float Tl[T_TOT];

  const int tid  = threadIdx.x;
  const int w    = tid >> 6;
  const int lane = tid & 63;
  const int nl   = lane & 15;
  const int q    = lane >> 4;
  const int b0   = blockIdx.x * BT;
  const int d0   = w * 16 + q * 4;

  const u32* pptr;
  int pstr, tstr, tbase = 0, twid = 0, tsub = 0;
  if (tid < PQN) {
    pptr = (const u32*)ipq + tid; pstr = LEN * PQN; tstr = PQN;
  } else {
    const int o = tid - PQN; int sel;
    if      (o < 5 ) { sel = 0; tbase = T_H; twid = 5; tsub = o;      }
    else if (o < 8 ) { sel = 1; tbase = T_W; twid = 3; tsub = o - 5;  }
    else if (o < 12) { sel = 2; tbase = T_M; twid = 4; tsub = o - 8;  }
    else             { sel = 3; tbase = T_Y; twid = 7; tsub = o - 12; }
    pptr = (const u32*)itime + sel; pstr = LEN * 4; tstr = 4;
  }
  pptr += (size_t)b0 * pstr;

  u32 pf[BT];
  #pragma unroll
  for (int bb = 0; bb < BT; ++bb) pf[bb] = pptr[(size_t)bb * pstr];

  half8 wif[8], wef[4], vdf[4][2], whf[4][8], whhf[4][2], wdf[2];
  {
    const f16* pw = wAll + OFF_WI + (w * 16 + nl) * 256 + q * 8;
    #pragma unroll
    for (int kt = 0; kt < 8; ++kt) wif[kt] = *(const half8*)(pw + kt * 32);
    const f16* pe = wAll + OFF_WE + (w * 16 + nl) * 128 + q * 8;
    #pragma unroll
    for (int kt = 0; kt < 4; ++kt) wef[kt] = *(const half8*)(pe + kt * 32);
    #pragma unroll
    for (int i = 0; i < 4; ++i) {
      const f16* pv = wAll + OFF_VD + ((w + 4*i) * 16 + nl) * 64 + q * 8;
      #pragma unroll
      for (int kt = 0; kt < 2; ++kt) vdf[i][kt] = *(const half8*)(pv + kt * 32);
      const f16* ph = wAll + OFF_WIH + ((w + 4*i) * 16 + nl) * 256 + q * 8;
      #pragma unroll
      for (int kt = 0; kt < 8; ++kt) whf[i][kt] = *(const half8*)(ph + kt * 32);
      const f16* pq = wAll + OFF_WHH + ((w + 4*i) * 16 + nl) * 64 + q * 8;
      #pragma unroll
      for (int kt = 0; kt < 2; ++kt) whhf[i][kt] = *(const half8*)(pq + kt * 32);
    }
    const f16* pd = wAll + OFF_WD + (w * 16 + nl) * 64 + q * 8;
    #pragma unroll
    for (int kt = 0; kt < 2; ++kt) wdf[kt] = *(const half8*)(pd + kt * 32);
  }

  float wib[4], vdb[16], ebs[16], wdb[4];
  #pragma unroll
  for (int r = 0; r < 4; ++r) { wib[r] = Wi_b[d0 + r]; wdb[r] = Wd_b[d0 + r]; }
  #pragma unroll
  for (int i = 0; i < 4; ++i)
    #pragma unroll
    for (int r = 0; r < 4; ++r) {
      vdb[i*4+r] = Vd_b[(w + 4*i) * 16 + q * 4 + r];
      ebs[i*4+r] = ebih[i * 64 + d0 + r] + ebhh[i * 64 + d0 + r];
    }

  for (int i = tid; i < BT * HS; i += 256) { Hl[i] = (f16)0.f; Cl[i] = (f16)0.f; }
  for (int i = tid; i < T_TOT; i += 256) {
    float v;
    if      (i < T_W) v = e_h[i];
    else if (i < T_M) v = e_w[i - T_W];
    else if (i < T_Y) v = e_m[i - T_M];
    else              v = e_y[i - T_Y];
    Tl[i] = v;
  }
  float creg[2][4];
  #pragma unroll
  for (int bt = 0; bt < 2; ++bt)
    #pragma unroll
    for (int r = 0; r < 4; ++r) creg[bt][r] = 0.f;
  bar_lds();

  for (int t = 0; t < LEN; ++t) {
    #pragma unroll
    for (int bb = 0; bb < BT; ++bb) {
      float v;
      if (tid < PQN) v = __uint_as_float(pf[bb]);
      else           v = Tl[tbase + (int)pf[bb] * twid + tsub];
      Xl[bb * XS + tid] = (f16)v;
    }
    if (t + 1 < LEN) {
      const u32* pp = pptr + (size_t)(t + 1) * tstr;
      #pragma unroll
      for (int bb = 0; bb < BT; ++bb) pf[bb] = pp[(size_t)bb * pstr];
    }
    bar_lds();

    #pragma unroll
    for (int bt = 0; bt < 2; ++bt) {
      const int row = bt * 16 + nl;
      f32x4 acc = {0.f, 0.f, 0.f, 0.f};
      const f16* xb = &Xl[row * XS + q * 8];
      #pragma unroll
      for (int kt = 0; kt < 8; ++kt)
        acc = __builtin_amdgcn_mfma_f32_16x16x32_f16(wif[kt], *(const half8*)(xb + kt * 32), acc, 0, 0, 0);
      const f16* hb = &Hl[row * HS + q * 8];
      const f16* cb = &Cl[row * HS + q * 8];
      half8 h0 = *(const half8*)hb, h1 = *(const half8*)(hb + 32);
      half8 c0 = *(const half8*)cb, c1 = *(const half8*)(cb + 32);
      acc = __builtin_amdgcn_mfma_f32_16x16x32_f16(wef[0], h0, acc, 0, 0, 0);
      acc = __builtin_amdgcn_mfma_f32_16x16x32_f16(wef[1], h1, acc, 0, 0, 0);
      acc = __builtin_amdgcn_mfma_f32_16x16x32_f16(wef[2], c0, acc, 0, 0, 0);
      acc = __builtin_amdgcn_mfma_f32_16x16x32_f16(wef[3], c1, acc, 0, 0, 0);
      f16x4 uv;
      #pragma unroll
      for (int r = 0; r < 4; ++r) uv[r] = (f16)tanhf_(acc[r] + wib[r]);
      *(f16x4*)(&Ul[row * HS + d0]) = uv;
      if (t > 0) {
        f32x4 aw = {0.f, 0.f, 0.f, 0.f};
        aw = __builtin_amdgcn_mfma_f32_16x16x32_f16(wdf[0], h0, aw, 0, 0, 0);
        aw = __builtin_amdgcn_mfma_f32_16x16x32_f16(wdf[1], h1, aw, 0, 0, 0);
        f16x4 wv;
        #pragma unroll
        for (int r = 0; r < 4; ++r) wv[r] = (f16)(aw[r] + wdb[r]);
        *(f16x4*)(&wmid[((size_t)(b0 + row) * LEN + (t - 1)) * HN + d0]) = wv;
      }
    }
    bar_lds();

    #pragma unroll
    for (int bt = 0; bt < 2; ++bt) {
      const int row = bt * 16 + nl;
      const f16* ub = &Ul[row * HS + q * 8];
      half8 u0 = *(const half8*)ub, u1 = *(const half8*)(ub + 32);
      float ee[16];
      #pragma unroll
      for (int i = 0; i < 4; ++i) {
        f32x4 acc = {0.f, 0.f, 0.f, 0.f};
        acc = __builtin_amdgcn_mfma_f32_16x16x32_f16(vdf[i][0], u0, acc, 0, 0, 0);
        acc = __builtin_amdgcn_mfma_f32_16x16x32_f16(vdf[i][1], u1, acc, 0, 0, 0);
        #pragma unroll
        for (int r = 0; r < 4; ++r)
          ee[i*4+r] = exp2f((acc[r] + vdb[i*4+r]) * 1.44269504f);
      }
      float s = 0.f;
      #pragma unroll
      for (int j = 0; j < 16; ++j) s += ee[j];
      s += __shfl_xor(s, 16, 64);
      s += __shfl_xor(s, 32, 64);
      if (lane < 16) Sred[bt * 64 + w * 16 + lane] = s;
      #pragma unroll
      for (int i = 0; i < 4; ++i) {
        const int k = (w + 4*i) * 16 + q * 4;
        f16x4 xv = *(const f16x4*)(&Xl[row * XS + k]);
        f16x4 pv;
        #pragma unroll
        for (int r = 0; r < 4; ++r) pv[r] = (f16)((float)xv[r] * ee[i*4+r]);
        *(f16x4*)(&Xl[row * XS + k]) = pv;
      }
    }
    bar_lds();

    f16x4 hstash[2], cstash[2];
    #pragma unroll
    for (int bt = 0; bt < 2; ++bt) {
      const int row = bt * 16 + nl;
      f32x4 g[4], gh[4];
      #pragma unroll
      for (int i = 0; i < 4; ++i) {
        g[i]  = (f32x4){0.f, 0.f, 0.f, 0.f};
        gh[i] = (f32x4){0.f, 0.f, 0.f, 0.f};
      }
      const f16* pb = &Xl[row * XS + q * 8];
      #pragma unroll
      for (int kt = 0; kt < 8; ++kt) {
        half8 bv = *(const half8*)(pb + kt * 32);
        #pragma unroll
        for (int i = 0; i < 4; ++i)
          g[i] = __builtin_amdgcn_mfma_f32_16x16x32_f16(whf[i][kt], bv, g[i], 0, 0, 0);
      }
      const f16* hb = &Hl[row * HS + q * 8];
      half8 h0 = *(const half8*)hb, h1 = *(const half8*)(hb + 32);
      #pragma unroll
      for (int i = 0; i < 4; ++i) {
        gh[i] = __builtin_amdgcn_mfma_f32_16x16x32_f16(whhf[i][0], h0, gh[i], 0, 0, 0);
        gh[i] = __builtin_amdgcn_mfma_f32_16x16x32_f16(whhf[i][1], h1, gh[i], 0, 0, 0);
      }
      const float inv = rcp_(Sred[bt*64 + nl]      + Sred[bt*64 + 16 + nl]
                           + Sred[bt*64 + 32 + nl] + Sred[bt*64 + 48 + nl]);
      f16x4 hv, cv;
      #pragma unroll
      for (int r = 0; r < 4; ++r) {
        const float gi = g[0][r] * inv + gh[0][r] + ebs[0  + r];
        const float gf = g[1][r] * inv + gh[1][r] + ebs[4  + r];
        const float gg = g[2][r] * inv + gh[2][r] + ebs[8  + r];
        const float go = g[3][r] * inv + gh[3][r] + ebs[12 + r];
        float c = sigm(gf) * creg[bt][r] + sigm(gi) * tanhf_(gg);
        creg[bt][r] = c;
        const float h = sigm(go) * tanhf_(c);
        hv[r] = (f16)h; cv[r] = (f16)c;
      }
      hstash[bt] = hv; cstash[bt] = cv;
      *(f16x4*)(&mid[((size_t)(b0 + row) * LEN + t) * HN + d0]) = hv;
    }
    bar_lds();
    #pragma unroll
    for (int bt = 0; bt < 2; ++bt) {
      const int row = bt * 16 + nl;
      *(f16x4*)(&Hl[row * HS + d0]) = hstash[bt];
      *(f16x4*)(&Cl[row * HS + d0]) = cstash[bt];
    }
  }

  bar_lds();
  #pragma unroll
  for (int bt = 0; bt < 2; ++bt) {
    const int row = bt * 16 + nl;
    const f16* hb = &Hl[row * HS + q * 8];
    half8 h0 = *(const half8*)hb, h1 = *(const half8*)(hb + 32);
    f32x4 aw = {0.f, 0.f, 0.f, 0.f};
    aw = __builtin_amdgcn_mfma_f32_16x16x32_f16(wdf[0], h0, aw, 0, 0, 0);
    aw = __builtin_amdgcn_mfma_f32_16x16x32_f16(wdf[1], h1, aw, 0, 0, 0);
    f16x4 wv;
    #pragma unroll
    for (int r = 0; r < 4; ++r) wv[r] = (f16)(aw[r] + wdb[r]);
    *(f16x4*)(&wmid[((size_t)(b0 + row) * LEN + (LEN - 1)) * HN + d0]) = wv;
  }
}

// ---------------- decoder v3: wm rows register-resident, tiny LDS ----------
__global__ __launch_bounds__(512) void dec_kernel(
    const f16* __restrict__ mids,     // cols 0..63 at stride MS per (b,t)
    const f16* __restrict__ wms,      // cols 0..63 at stride MS per (b,t)
    const int MS,
    const float* __restrict__ lblp,
    const float* __restrict__ Wd2_w,  // (64,2)
    const float* __restrict__ Vdt_w,  // (1,64)
    const float* __restrict__ Vdt_b,  // (1)
    const float* __restrict__ dWih,   // (4,65)
    const float* __restrict__ dWhh,   // (4,1)
    const float* __restrict__ dbih, const float* __restrict__ dbhh,
    float* __restrict__ out)          // (B,LD)
{
  __shared__ __attribute__((aligned(16))) float qv[DW][HN];
  __shared__ __attribute__((aligned(16))) float vs[HN];
  __shared__ __attribute__((aligned(16))) float ws4[4 * 65];

  const int w    = threadIdx.x >> 6;
  const int lane = threadIdx.x & 63;
  const int b    = blockIdx.x * DW + w;

  if (threadIdx.x < HN)     vs[threadIdx.x]  = Vdt_w[threadIdx.x];
  if (threadIdx.x < 4 * 65) ws4[threadIdx.x] = dWih[threadIdx.x];

  half8 wmr[8];
  if (lane < LEN) {
    const f16* p = wms + ((size_t)b * LEN + lane) * MS;
    #pragma unroll
    for (int k = 0; k < 8; ++k) wmr[k] = *(const half8*)(p + k * 8);
  } else {
    #pragma unroll
    for (int k = 0; k < 8; ++k)
      #pragma unroll
      for (int e = 0; e < 8; ++e) wmr[k][e] = (f16)0.f;
  }
  __syncthreads();

  float macc[4] = {0.f, 0.f, 0.f, 0.f};
  if (lane < LEN) {
    const f16* mrow = mids + ((size_t)b * LEN + lane) * MS;
    #pragma unroll
    for (int k8 = 0; k8 < 8; ++k8) {
      half8 mv = *(const half8*)(mrow + k8 * 8);
      #pragma unroll
      for (int e = 0; e < 8; ++e) {
        const float m = (float)mv[e];
        #pragma unroll
        for (int j = 0; j < 4; ++j) macc[j] += ws4[j * 65 + k8 * 8 + e] * m;
      }
    }
  }

  const float dpin = lblp[b * LEN + (LEN - 1)];
  const float w20 = Wd2_w[2 * lane];
  const float w21 = Wd2_w[2 * lane + 1];
  const float vdtb = Vdt_b[0];
  float wxx[4], whh4[4], bb4[4];
  #pragma unroll
  for (int j = 0; j < 4; ++j) {
    wxx[j]  = dWih[j * 65 + 64];
    whh4[j] = dWhh[j];
    bb4[j]  = dbih[j] + dbhh[j];
  }

  float hi = 0.0f, ci = 0.0f;
  for (int s = 0; s < LDN; ++s) {
    qv[w][lane] = w20 * hi + w21 * ci;

    float p0 = 0.f, p1 = 0.f, p2 = 0.f, p3 = 0.f;
    if (lane < LEN) {
      float acc = 0.f;
      #pragma unroll
      for (int k8 = 0; k8 < 8; ++k8) {
        float4 qa = *(const float4*)&qv[w][k8 * 8];
        float4 qb = *(const float4*)&qv[w][k8 * 8 + 4];
        float4 va = *(const float4*)&vs[k8 * 8];
        float4 vb = *(const float4*)&vs[k8 * 8 + 4];
        half8 wv = wmr[k8];
        acc += tanhf_(qa.x + (float)wv[0]) * va.x
             + tanhf_(qa.y + (float)wv[1]) * va.y
             + tanhf_(qa.z + (float)wv[2]) * va.z
             + tanhf_(qa.w + (float)wv[3]) * va.w
             + tanhf_(qb.x + (float)wv[4]) * vb.x
             + tanhf_(qb.y + (float)wv[5]) * vb.y
             + tanhf_(qb.z + (float)wv[6]) * vb.z
             + tanhf_(qb.w + (float)wv[7]) * vb.w;
      }
      const float score = acc + vdtb;
      p0 = score * macc[0]; p1 = score * macc[1];
      p2 = score * macc[2]; p3 = score * macc[3];
    }
    #pragma unroll
    for (int off = 32; off >= 1; off >>= 1) {
      p0 += __shfl_xor(p0, off, 64);
      p1 += __shfl_xor(p1, off, 64);
      p2 += __shfl_xor(p2, off, 64);
      p3 += __shfl_xor(p3, off, 64);
    }
    const float g0 = p0 + wxx[0] * dpin + bb4[0] + whh4[0] * hi;
    const float g1 = p1 + wxx[1] * dpin + bb4[1] + whh4[1] * hi;
    const float g2 = p2 + wxx[2] * dpin + bb4[2] + whh4[2] * hi;
    const float g3 = p3 + wxx[3] * dpin + bb4[3] + whh4[3] * hi;
    ci = sigm(g1) * ci + sigm(g0) * tanhf_(g2);
    hi = sigm(g3) * tanhf_(ci);
    if (lane == 0) out[b * LDN + s] = hi;
  }
}

extern "C" void kernel_launch(void* const* d_in, const int* in_sizes, int n_in,
                              void* d_out, int out_size, void* d_ws, size_t ws_size,
                              hipStream_t stream) {
  (void)in_sizes; (void)n_in; (void)out_size;
  const float* ipq   = (const float*)d_in[0];
  const float* lblp  = (const float*)d_in[1];
  const float* e_h   = (const float*)d_in[2];
  const float* e_w   = (const float*)d_in[3];
  const float* e_m   = (const float*)d_in[4];
  const float* e_y   = (const float*)d_in[5];
  const float* Wi_w  = (const float*)d_in[6];
  const float* Wi_b  = (const float*)d_in[7];
  const float* We_w  = (const float*)d_in[8];
  const float* Vd_w  = (const float*)d_in[9];
  const float* Vd_b  = (const float*)d_in[10];
  const float* eWih  = (const float*)d_in[11];
  const float* eWhh  = (const float*)d_in[12];
  const float* ebih  = (const float*)d_in[13];
  const float* ebhh  = (const float*)d_in[14];
  const float* Wd_w  = (const float*)d_in[15];
  const float* Wd_b  = (const float*)d_in[16];
  const float* Wd2_w = (const float*)d_in[17];
  const float* Vdt_w = (const float*)d_in[18];
  const float* Vdt_b = (const float*)d_in[19];
  const float* dWih  = (const float*)d_in[20];
  const float* dWhh  = (const float*)d_in[21];
  const float* dbih  = (const float*)d_in[22];
  const float* dbhh  = (const float*)d_in[23];
  const int* itime   = (const int*)d_in[24];
  float* out = (float*)d_out;

  const size_t xpreB = (size_t)BB * LEN * XPS * 2;   // 167.77 MB
  const size_t wcvtB = (size_t)W_TOTAL * 2;          // 254 KB

  if (ws_size >= xpreB + wcvtB) {
    f16* xpre = (f16*)d_ws;
    f16* wcvt = (f16*)((char*)d_ws + xpreB);
    prep_all<<<dim3(PREP_BLOCKS + CONV_BLOCKS), dim3(256), 0, stream>>>(
        ipq, e_h, e_w, e_m, e_y, itime, xpre,
        Wi_w, We_w, Vd_w, eWih, eWhh, Wd_w, wcvt);
    enc_x<<<dim3(ENC_BLOCKS), dim3(512), 0, stream>>>(
        xpre, Wi_b, Vd_b, ebih, ebhh, Wd_b, wcvt, xpre);
    dec_kernel<<<dim3(DEC_BLOCKS), dim3(512), 0, stream>>>(
        xpre, xpre + 64, XPS, lblp, Wd2_w, Vdt_w, Vdt_b,
        dWih, dWhh, dbih, dbhh, out);
  } else {
    const size_t midB = (size_t)BB * LEN * HN * 2;   // 41.94 MB
    f16* mid  = (f16*)d_ws;
    f16* wmid = (f16*)((char*)d_ws + midB);
    f16* wcvt = (f16*)((char*)d_ws + 2 * midB);
    conv_w<<<dim3(CONV_BLOCKS), dim3(256), 0, stream>>>(
        Wi_w, We_w, Vd_w, eWih, eWhh, Wd_w, wcvt);
    enc_fb<<<dim3(ENC_BLOCKS), dim3(256), 0, stream>>>(
        ipq, e_h, e_w, e_m, e_y, Wi_b, Vd_b, ebih, ebhh, Wd_b, wcvt, itime,
        mid, wmid);
    dec_kernel<<<dim3(DEC_BLOCKS), dim3(512), 0, stream>>>(
        mid, wmid, HN, lblp, Wd2_w, Vdt_w, Vdt_b,
        dWih, dWhh, dbih, dbhh, out);
  }
}

// Round 5
// 828.793 us; speedup vs baseline: 1.0647x; 1.0647x over previous
//
#include <hip/hip_runtime.h>

#define BB   8192
#define LEN  40
#define LDN  12
#define PQN  237
#define INN  256
#define HN   64
#define BT   32                 // encoder batches per block (2 MFMA n-tiles)
#define ENC_BLOCKS (BB / BT)    // 256 -> 1 block/CU
#define DW   8                  // decoder batches per block (1 wave each)
#define DEC_BLOCKS (BB / DW)    // 1024
#define XPS  256                // xpre row stride in f16 (power of 2)

typedef unsigned int  u32;
typedef _Float16 f16;
typedef f16  half8 __attribute__((ext_vector_type(8)));
typedef f16  f16x4 __attribute__((ext_vector_type(4)));
typedef float f32x4 __attribute__((ext_vector_type(4)));

#define XS 264   // X/P LDS row stride (f16): reads 2-way max bank aliasing
#define HS 72    // U/H/C LDS row stride (f16): 2-way max

// weight offsets (f16 elements) in converted buffer
#define OFF_WI   0
#define OFF_WE   16384
#define OFF_VD   24576
#define OFF_WIH  40960
#define OFF_WHH  106496
#define OFF_WD   122880
#define W_TOTAL  126976

// LDS-staged embedding tables (f32) for fallback encoder
#define T_H   0
#define T_W   120
#define T_M   144
#define T_Y   196
#define T_TOT 574

#define PREP_BLOCKS (BB * LEN / 32)          // 10240
#define CONV_BLOCKS ((W_TOTAL + 255) / 256)  // 496

__device__ __forceinline__ float rcp_(float x){
#if __has_builtin(__builtin_amdgcn_rcpf)
  return __builtin_amdgcn_rcpf(x);
#else
  return 1.0f / x;
#endif
}
__device__ __forceinline__ float sigm(float x){
  return rcp_(1.0f + exp2f(-1.44269504f * x));
}
// tanh = 1 - 2/(e^{2x}+1); exp2 over/underflow saturates cleanly, no clamp.
__device__ __forceinline__ float tanhf_(float x){
  float e = exp2f(2.88539008f * x);
  return 1.0f - 2.0f * rcp_(e + 1.0f);
}

// lgkm-only barrier: LDS producer->consumer ordering WITHOUT draining vmcnt.
__device__ __forceinline__ void bar_lds(){
  asm volatile("s_waitcnt lgkmcnt(0)" ::: "memory");
  __builtin_amdgcn_s_barrier();
  asm volatile("" ::: "memory");
}

// ---------------- weight f32 -> f16 conversion (fallback path) -------------
__global__ __launch_bounds__(256) void conv_w(
    const float* __restrict__ Wi, const float* __restrict__ We,
    const float* __restrict__ Vd, const float* __restrict__ Wih,
    const float* __restrict__ Whh, const float* __restrict__ Wd,
    f16* __restrict__ dst)
{
  int i = blockIdx.x * 256 + threadIdx.x;
  if (i >= W_TOTAL) return;
  float v;
  if      (i < OFF_WE)  v = Wi [i - OFF_WI ];
  else if (i < OFF_VD)  v = We [i - OFF_WE ];
  else if (i < OFF_WIH) v = Vd [i - OFF_VD ];
  else if (i < OFF_WHH) v = Wih[i - OFF_WIH];
  else if (i < OFF_WD)  v = Whh[i - OFF_WHH];
  else                  v = Wd [i - OFF_WD ];
  dst[i] = (f16)v;
}

// ---------------- prep_all: X materialization + fused weight convert -------
__global__ __launch_bounds__(256) void prep_all(
    const float* __restrict__ ipq,
    const float* __restrict__ e_h, const float* __restrict__ e_w,
    const float* __restrict__ e_m, const float* __restrict__ e_y,
    const int*  __restrict__ itime,
    f16* __restrict__ xpre,
    const float* __restrict__ Wi, const float* __restrict__ We,
    const float* __restrict__ Vd, const float* __restrict__ Wih,
    const float* __restrict__ Whh, const float* __restrict__ Wd,
    f16* __restrict__ wdst)
{
  if (blockIdx.x >= PREP_BLOCKS) {
    int i = (blockIdx.x - PREP_BLOCKS) * 256 + threadIdx.x;
    if (i >= W_TOTAL) return;
    float v;
    if      (i < OFF_WE)  v = Wi [i - OFF_WI ];
    else if (i < OFF_VD)  v = We [i - OFF_WE ];
    else if (i < OFF_WIH) v = Vd [i - OFF_VD ];
    else if (i < OFF_WHH) v = Wih[i - OFF_WIH];
    else if (i < OFF_WD)  v = Whh[i - OFF_WHH];
    else                  v = Wd [i - OFF_WD ];
    wdst[i] = (f16)v;
    return;
  }
  const int wv = threadIdx.x >> 6, l = threadIdx.x & 63;
  const size_t row0 = (size_t)blockIdx.x * 32 + (size_t)wv * 8;
  int4 itv[8];
  #pragma unroll
  for (int r = 0; r < 8; ++r)
    itv[r] = *(const int4*)(itime + (row0 + r) * 4);
  #pragma unroll
  for (int r = 0; r < 8; ++r) {
    const size_t row = row0 + r;               // = b*LEN + t
    const float* src = ipq + row * PQN;
    f16* dst = xpre + row * XPS;
    #pragma unroll
    for (int k = 0; k < 3; ++k) {
      const int c = k * 64 + l;
      dst[c] = (f16)src[c];
    }
    {
      const int c = 192 + l;
      float v;
      if (c < PQN) v = src[c];
      else {
        const int o = c - PQN;
        if      (o < 5 ) v = e_h[itv[r].x * 5 + o];
        else if (o < 8 ) v = e_w[itv[r].y * 3 + (o - 5)];
        else if (o < 12) v = e_m[itv[r].z * 4 + (o - 8)];
        else             v = e_y[itv[r].w * 7 + (o - 12)];
      }
      dst[c] = (f16)v;
    }
  }
}

// ---------------- encoder v5: 2 waves/SIMD, zero-spill weight split --------
// AGPR (128): whf[4][8] = all four Wih gate slices.  Everything else (Wi,
// We, Vd, Whh, Wd) in LDS at [tile][kt][lane] (lane-contiguous b128,
// conflict-free).  Working VGPR ~116 < 128 -> no scratch.  Single-buffered
// Xl/Hl/Cl + stash => 4 lgkm-only barriers/step.  ph2 acc chain split in 2.
__global__ __launch_bounds__(512, 2) void enc_x(
    const f16* __restrict__ xpre,
    const float* __restrict__ Wi_b,   // (64)
    const float* __restrict__ Vd_b,   // (256)
    const float* __restrict__ ebih, const float* __restrict__ ebhh, // (256)
    const float* __restrict__ Wd_b,   // (64)
    const f16*  __restrict__ wAll,
    f16* __restrict__ xout)           // == xpre (overlay)
{
  __shared__ __attribute__((aligned(16))) f16 Xl[BT * XS];       // 16.9 KB
  __shared__ __attribute__((aligned(16))) f16 Ul[BT * HS];       //  4.6 KB
  __shared__ __attribute__((aligned(16))) f16 Hl[BT * HS];       //  4.6 KB
  __shared__ __attribute__((aligned(16))) f16 Cl[BT * HS];       //  4.6 KB
  __shared__ float Sred[2 * 64];                                 //  0.5 KB
  __shared__ __attribute__((aligned(16))) f16 WiL[4 * 8 * 64 * 8];  // 32 KB
  __shared__ __attribute__((aligned(16))) f16 WeL[4 * 4 * 64 * 8];  // 16 KB
  __shared__ __attribute__((aligned(16))) f16 VdL[16 * 2 * 64 * 8]; // 32 KB
  __shared__ __attribute__((aligned(16))) f16 WhL[16 * 2 * 64 * 8]; // 32 KB
  __shared__ __attribute__((aligned(16))) f16 WdL[4 * 2 * 64 * 8];  //  8 KB
  __shared__ float VdbL[256];
  __shared__ float EbsL[256];

  const int tid  = threadIdx.x;
  const int w    = tid >> 6;
  const int lane = tid & 63;
  const int nl   = lane & 15;
  const int q    = lane >> 4;
  const int wsub = w & 3;
  const int bt   = w >> 2;
  const int b0   = blockIdx.x * BT;
  const int d0   = wsub * 16 + q * 4;
  const int row  = bt * 16 + nl;     // batch row (n-dim) this wave's MFMA

  // staging map (512 thr): row r0(+16), 16B chunk off
  const int r0  = tid >> 5;          // 0..15
  const int off = tid & 31;
  const f16* gb0 = xpre + ((size_t)(b0 + r0     ) * LEN) * XPS + off * 8;
  const f16* gb1 = xpre + ((size_t)(b0 + r0 + 16) * LEN) * XPS + off * 8;
  const u32 lwa = (u32)(r0 * XS + off * 8);
  const u32 lwb = (u32)((r0 + 16) * XS + off * 8);

  // mid streaming map: one f16x4 per thread (32 rows x 64 cols)
  const int orow = tid >> 4;
  const int oc4  = (tid & 15) * 4;

  // ---- issue t=0 staging loads first ----
  half8 sr0 = *(const half8*)gb0;
  half8 sr1 = *(const half8*)gb1;

  // ---- register weights: Wih slices only (128 AGPR exactly) ----
  half8 whf[4][8];
  #pragma unroll
  for (int i = 0; i < 4; ++i) {
    const f16* ph = wAll + OFF_WIH + ((wsub + 4*i) * 16 + nl) * 256 + q * 8;
    #pragma unroll
    for (int kt = 0; kt < 8; ++kt) whf[i][kt] = *(const half8*)(ph + kt * 32);
  }
  float wib[4], wdb[4];
  #pragma unroll
  for (int r = 0; r < 4; ++r) { wib[r] = Wi_b[d0 + r]; wdb[r] = Wd_b[d0 + r]; }

  // ---- LDS weights: [tile][kt][lane] fragment layout ----
  for (int s = tid; s < 4 * 8 * 64; s += 512) {     // Wi: 4 tiles, kt=8
    const int tile = s >> 9, kt = (s >> 6) & 7, ln = s & 63;
    *(half8*)(&WiL[(size_t)s * 8]) = *(const half8*)(
        wAll + OFF_WI + (tile * 16 + (ln & 15)) * 256 + (ln >> 4) * 8 + kt * 32);
  }
  for (int s = tid; s < 4 * 4 * 64; s += 512) {     // We: 4 tiles, j=4
    const int tile = s >> 8, j = (s >> 6) & 3, ln = s & 63;
    *(half8*)(&WeL[(size_t)s * 8]) = *(const half8*)(
        wAll + OFF_WE + (tile * 16 + (ln & 15)) * 128 + (ln >> 4) * 8 + j * 32);
  }
  for (int s = tid; s < 16 * 2 * 64; s += 512) {    // Vd: 16 tiles, kt=2
    const int tile = s >> 7, kt = (s >> 6) & 1, ln = s & 63;
    *(half8*)(&VdL[(size_t)s * 8]) = *(const half8*)(
        wAll + OFF_VD + (tile * 16 + (ln & 15)) * 64 + (ln >> 4) * 8 + kt * 32);
  }
  for (int s = tid; s < 16 * 2 * 64; s += 512) {    // Whh: 16 tiles, kt=2
    const int tile = s >> 7, kt = (s >> 6) & 1, ln = s & 63;
    *(half8*)(&WhL[(size_t)s * 8]) = *(const half8*)(
        wAll + OFF_WHH + (tile * 16 + (ln & 15)) * 64 + (ln >> 4) * 8 + kt * 32);
  }
  for (int s = tid; s < 4 * 2 * 64; s += 512) {     // Wd: 4 tiles, kt=2
    const int tile = s >> 7, kt = (s >> 6) & 1, ln = s & 63;
    *(half8*)(&WdL[(size_t)s * 8]) = *(const half8*)(
        wAll + OFF_WD + (tile * 16 + (ln & 15)) * 64 + (ln >> 4) * 8 + kt * 32);
  }
  if (tid < 256) {
    VdbL[tid] = Vd_b[tid];
    EbsL[tid] = ebih[tid] + ebhh[tid];
  }
  for (int i = tid; i < BT * HS; i += 512) {
    Hl[i] = (f16)0.f; Cl[i] = (f16)0.f;
  }
  float creg[4] = {0.f, 0.f, 0.f, 0.f};
  bar_lds();

  for (int t = 0; t < LEN; ++t) {
    // ---- top: staged regs -> Xl; reissue prefetch for t+1 ----
    *(half8*)(&Xl[lwa]) = sr0;
    *(half8*)(&Xl[lwb]) = sr1;
    if (t + 1 < LEN) {
      sr0 = *(const half8*)(gb0 + (size_t)(t + 1) * XPS);
      sr1 = *(const half8*)(gb1 + (size_t)(t + 1) * XPS);
    }
    bar_lds();   // A: Xl ready; Hl/Cl(t-1) ready (written after D(t-1))

    // ---- phase 2: U = tanh(Wi@X + We@[H;C] + b); wm(t-1) direct store ----
    {
      // split accumulator chains: depth 6 each instead of 12
      f32x4 a0 = {0.f, 0.f, 0.f, 0.f}, a1 = {0.f, 0.f, 0.f, 0.f};
      const f16* xb = &Xl[row * XS + q * 8];
      #pragma unroll
      for (int kt = 0; kt < 4; ++kt)
        a0 = __builtin_amdgcn_mfma_f32_16x16x32_f16(
            *(const half8*)(&WiL[((wsub * 8 + kt) * 64 + lane) * 8]),
            *(const half8*)(xb + kt * 32), a0, 0, 0, 0);
      #pragma unroll
      for (int kt = 4; kt < 8; ++kt)
        a1 = __builtin_amdgcn_mfma_f32_16x16x32_f16(
            *(const half8*)(&WiL[((wsub * 8 + kt) * 64 + lane) * 8]),
            *(const half8*)(xb + kt * 32), a1, 0, 0, 0);
      const f16* hb = &Hl[row * HS + q * 8];
      const f16* cb = &Cl[row * HS + q * 8];
      half8 h0 = *(const half8*)hb, h1 = *(const half8*)(hb + 32);
      half8 c0 = *(const half8*)cb, c1 = *(const half8*)(cb + 32);
      a0 = __builtin_amdgcn_mfma_f32_16x16x32_f16(
          *(const half8*)(&WeL[((wsub * 4 + 0) * 64 + lane) * 8]), h0, a0, 0, 0, 0);
      a1 = __builtin_amdgcn_mfma_f32_16x16x32_f16(
          *(const half8*)(&WeL[((wsub * 4 + 1) * 64 + lane) * 8]), h1, a1, 0, 0, 0);
      a0 = __builtin_amdgcn_mfma_f32_16x16x32_f16(
          *(const half8*)(&WeL[((wsub * 4 + 2) * 64 + lane) * 8]), c0, a0, 0, 0, 0);
      a1 = __builtin_amdgcn_mfma_f32_16x16x32_f16(
          *(const half8*)(&WeL[((wsub * 4 + 3) * 64 + lane) * 8]), c1, a1, 0, 0, 0);
      f16x4 uv;
      #pragma unroll
      for (int r = 0; r < 4; ++r) uv[r] = (f16)tanhf_(a0[r] + a1[r] + wib[r]);
      *(f16x4*)(&Ul[row * HS + d0]) = uv;
      if (t > 0) {   // wm(t-1): direct scattered 8B store (proven in r2)
        f32x4 aw = {0.f, 0.f, 0.f, 0.f};
        aw = __builtin_amdgcn_mfma_f32_16x16x32_f16(
            *(const half8*)(&WdL[((wsub * 2 + 0) * 64 + lane) * 8]), h0, aw, 0, 0, 0);
        aw = __builtin_amdgcn_mfma_f32_16x16x32_f16(
            *(const half8*)(&WdL[((wsub * 2 + 1) * 64 + lane) * 8]), h1, aw, 0, 0, 0);
        f16x4 wv;
        #pragma unroll
        for (int r = 0; r < 4; ++r) wv[r] = (f16)(aw[r] + wdb[r]);
        *(f16x4*)(&xout[((size_t)(b0 + row) * LEN + (t - 1)) * XPS + 64 + d0]) = wv;
      }
    }
    bar_lds();   // B: Ul ready

    // ---- phase 3: stream mid(t-1); ee = exp(Vd@U+b); P = X*ee ----
    if (t > 0) {   // coalesced f16x4: 16 threads -> 128B contiguous
      f16x4 hv4 = *(const f16x4*)(&Hl[orow * HS + oc4]);
      *(f16x4*)(&xout[((size_t)(b0 + orow) * LEN + (t - 1)) * XPS + oc4]) = hv4;
    }
    {
      const f16* ub = &Ul[row * HS + q * 8];
      half8 u0 = *(const half8*)ub, u1 = *(const half8*)(ub + 32);
      float s = 0.f;
      #pragma unroll
      for (int i = 0; i < 4; ++i) {
        const int tile = wsub + 4 * i;
        f32x4 acc = {0.f, 0.f, 0.f, 0.f};
        acc = __builtin_amdgcn_mfma_f32_16x16x32_f16(
            *(const half8*)(&VdL[((tile * 2 + 0) * 64 + lane) * 8]), u0, acc, 0, 0, 0);
        acc = __builtin_amdgcn_mfma_f32_16x16x32_f16(
            *(const half8*)(&VdL[((tile * 2 + 1) * 64 + lane) * 8]), u1, acc, 0, 0, 0);
        const int k = tile * 16 + q * 4;
        f16x4 xv = *(const f16x4*)(&Xl[row * XS + k]);
        f16x4 pv;
        float ee[4];
        #pragma unroll
        for (int r = 0; r < 4; ++r) {
          ee[r] = exp2f((acc[r] + VdbL[k + r]) * 1.44269504f);
          s += ee[r];
          pv[r] = (f16)((float)xv[r] * ee[r]);
        }
        *(f16x4*)(&Xl[row * XS + k]) = pv;   // unnormalized P in place
      }
      s += __shfl_xor(s, 16, 64);
      s += __shfl_xor(s, 32, 64);
      if (lane < 16) Sred[bt * 64 + wsub * 16 + lane] = s;
    }
    bar_lds();   // C: P + Sred ready

    // ---- phase 4: gates; LSTM; stash; barrier D; H/C writes ----
    f16x4 hv, cv;
    {
      f32x4 g[4], gh[4];
      #pragma unroll
      for (int i = 0; i < 4; ++i) {
        g[i]  = (f32x4){0.f, 0.f, 0.f, 0.f};
        gh[i] = (f32x4){0.f, 0.f, 0.f, 0.f};
      }
      const f16* pb = &Xl[row * XS + q * 8];
      #pragma unroll
      for (int kt = 0; kt < 8; ++kt) {
        half8 bv = *(const half8*)(pb + kt * 32);
        #pragma unroll
        for (int i = 0; i < 4; ++i)
          g[i] = __builtin_amdgcn_mfma_f32_16x16x32_f16(whf[i][kt], bv, g[i], 0, 0, 0);
      }
      const f16* hb = &Hl[row * HS + q * 8];
      half8 h0 = *(const half8*)hb, h1 = *(const half8*)(hb + 32);
      #pragma unroll
      for (int i = 0; i < 4; ++i) {
        const int tile = wsub + 4 * i;
        gh[i] = __builtin_amdgcn_mfma_f32_16x16x32_f16(
            *(const half8*)(&WhL[((tile * 2 + 0) * 64 + lane) * 8]), h0, gh[i], 0, 0, 0);
        gh[i] = __builtin_amdgcn_mfma_f32_16x16x32_f16(
            *(const half8*)(&WhL[((tile * 2 + 1) * 64 + lane) * 8]), h1, gh[i], 0, 0, 0);
      }
      const float inv = rcp_(Sred[bt*64 + nl]      + Sred[bt*64 + 16 + nl]
                           + Sred[bt*64 + 32 + nl] + Sred[bt*64 + 48 + nl]);
      #pragma unroll
      for (int r = 0; r < 4; ++r) {
        const float gi = g[0][r] * inv + gh[0][r] + EbsL[0   + d0 + r];
        const float gf = g[1][r] * inv + gh[1][r] + EbsL[64  + d0 + r];
        const float gg = g[2][r] * inv + gh[2][r] + EbsL[128 + d0 + r];
        const float go = g[3][r] * inv + gh[3][r] + EbsL[192 + d0 + r];
        float c = sigm(gf) * creg[r] + sigm(gi) * tanhf_(gg);
        creg[r] = c;
        const float h = sigm(go) * tanhf_(c);
        hv[r] = (f16)h; cv[r] = (f16)c;
      }
    }
    bar_lds();   // D: all waves done reading P/H -> safe to overwrite H/C
    *(f16x4*)(&Hl[row * HS + d0]) = hv;
    *(f16x4*)(&Cl[row * HS + d0]) = cv;
  }

  // ---- epilogue: wm(LEN-1) + stream final mid (Hl = H_{LEN-1}) ----
  bar_lds();
  {
    const f16* hb = &Hl[row * HS + q * 8];
    half8 h0 = *(const half8*)hb, h1 = *(const half8*)(hb + 32);
    f32x4 aw = {0.f, 0.f, 0.f, 0.f};
    aw = __builtin_amdgcn_mfma_f32_16x16x32_f16(
        *(const half8*)(&WdL[((wsub * 2 + 0) * 64 + lane) * 8]), h0, aw, 0, 0, 0);
    aw = __builtin_amdgcn_mfma_f32_16x16x32_f16(
        *(const half8*)(&WdL[((wsub * 2 + 1) * 64 + lane) * 8]), h1, aw, 0, 0, 0);
    f16x4 wv;
    #pragma unroll
    for (int r = 0; r < 4; ++r) wv[r] = (f16)(aw[r] + wdb[r]);
    *(f16x4*)(&xout[((size_t)(b0 + row) * LEN + (LEN - 1)) * XPS + 64 + d0]) = wv;
    f16x4 hv4 = *(const f16x4*)(&Hl[orow * HS + oc4]);
    *(f16x4*)(&xout[((size_t)(b0 + orow) * LEN + (LEN - 1)) * XPS + oc4]) = hv4;
  }
}

// ---------------- fallback encoder (round-2, proven): used if ws small -----
__global__ __launch_bounds__(256, 1) void enc_fb(
    const float* __restrict__ ipq,
    const float* __restrict__ e_h, const float* __restrict__ e_w,
    const float* __restrict__ e_m, const float* __restrict__ e_y,
    const float* __restrict__ Wi_b, const float* __restrict__ Vd_b,
    const float* __restrict__ ebih, const float* __restrict__ ebhh,
    const float* __restrict__ Wd_b, const f16* __restrict__ wAll,
    const int*  __restrict__ itime,
    f16* __restrict__ mid, f16* __restrict__ wmid)
{
  __shared__ __attribute__((aligned(16))) f16 Xl[BT * XS];
  __shared__ __attribute__((aligned(16))) f16 Ul[BT * HS];
  __shared__ __attribute__((aligned(16))) f16 Hl[BT * HS];
  __shared__ __attribute__((aligned(16))) f16 Cl[BT * HS];
  __shared__ float Sred[2 * 64];
  __shared__ float Tl[T_TOT];

  const int tid  = threadIdx.x;
  const int w    = tid >> 6;
  const int lane = tid & 63;
  const int nl   = lane & 15;
  const int q    = lane >> 4;
  const int b0   = blockIdx.x * BT;
  const int d0   = w * 16 + q * 4;

  const u32* pptr;
  int pstr, tstr, tbase = 0, twid = 0, tsub = 0;
  if (tid < PQN) {
    pptr = (const u32*)ipq + tid; pstr = LEN * PQN; tstr = PQN;
  } else {
    const int o = tid - PQN; int sel;
    if      (o < 5 ) { sel = 0; tbase = T_H; twid = 5; tsub = o;      }
    else if (o < 8 ) { sel = 1; tbase = T_W; twid = 3; tsub = o - 5;  }
    else if (o < 12) { sel = 2; tbase = T_M; twid = 4; tsub = o - 8;  }
    else             { sel = 3; tbase = T_Y; twid = 7; tsub = o - 12; }
    pptr = (const u32*)itime + sel; pstr = LEN * 4; tstr = 4;
  }
  pptr += (size_t)b0 * pstr;

  u32 pf[BT];
  #pragma unroll
  for (int bb = 0; bb < BT; ++bb) pf[bb] = pptr[(size_t)bb * pstr];

  half8 wif[8], wef[4], vdf[4][2], whf[4][8], whhf[4][2], wdf[2];
  {
    const f16* pw = wAll + OFF_WI + (w * 16 + nl) * 256 + q * 8;
    #pragma unroll
    for (int kt = 0; kt < 8; ++kt) wif[kt] = *(const half8*)(pw + kt * 32);
    const f16* pe = wAll + OFF_WE + (w * 16 + nl) * 128 + q * 8;
    #pragma unroll
    for (int kt = 0; kt < 4; ++kt) wef[kt] = *(const half8*)(pe + kt * 32);
    #pragma unroll
    for (int i = 0; i < 4; ++i) {
      const f16* pv = wAll + OFF_VD + ((w + 4*i) * 16 + nl) * 64 + q * 8;
      #pragma unroll
      for (int kt = 0; kt < 2; ++kt) vdf[i][kt] = *(const half8*)(pv + kt * 32);
      const f16* ph = wAll + OFF_WIH + ((w + 4*i) * 16 + nl) * 256 + q * 8;
      #pragma unroll
      for (int kt = 0; kt < 8; ++kt) whf[i][kt] = *(const half8*)(ph + kt * 32);
      const f16* pq = wAll + OFF_WHH + ((w + 4*i) * 16 + nl) * 64 + q * 8;
      #pragma unroll
      for (int kt = 0; kt < 2; ++kt) whhf[i][kt] = *(const half8*)(pq + kt * 32);
    }
    const f16* pd = wAll + OFF_WD + (w * 16 + nl) * 64 + q * 8;
    #pragma unroll
    for (int kt = 0; kt < 2; ++kt) wdf[kt] = *(const half8*)(pd + kt * 32);
  }

  float wib[4], vdb[16], ebs[16], wdb[4];
  #pragma unroll
  for (int r = 0; r < 4; ++r) { wib[r] = Wi_b[d0 + r]; wdb[r] = Wd_b[d0 + r]; }
  #pragma unroll
  for (int i = 0; i < 4; ++i)
    #pragma unroll
    for (int r = 0; r < 4; ++r) {
      vdb[i*4+r] = Vd_b[(w + 4*i) * 16 + q * 4 + r];
      ebs[i*4+r] = ebih[i * 64 + d0 + r] + ebhh[i * 64 + d0 + r];
    }

  for (int i = tid; i < BT * HS; i += 256) { Hl[i] = (f16)0.f; Cl[i] = (f16)0.f; }
  for (int i = tid; i < T_TOT; i += 256) {
    float v;
    if      (i < T_W) v = e_h[i];
    else if (i < T_M) v = e_w[i - T_W];
    else if (i < T_Y) v = e_m[i - T_M];
    else              v = e_y[i - T_Y];
    Tl[i] = v;
  }
  float creg[2][4];
  #pragma unroll
  for (int bt = 0; bt < 2; ++bt)
    #pragma unroll
    for (int r = 0; r < 4; ++r) creg[bt][r] = 0.f;
  bar_lds();

  for (int t = 0; t < LEN; ++t) {
    #pragma unroll
    for (int bb = 0; bb < BT; ++bb) {
      float v;
      if (tid < PQN) v = __uint_as_float(pf[bb]);
      else           v = Tl[tbase + (int)pf[bb] * twid + tsub];
      Xl[bb * XS + tid] = (f16)v;
    }
    if (t + 1 < LEN) {
      const u32* pp = pptr + (size_t)(t + 1) * tstr;
      #pragma unroll
      for (int bb = 0; bb < BT; ++bb) pf[bb] = pp[(size_t)bb * pstr];
    }
    bar_lds();

    #pragma unroll
    for (int bt = 0; bt < 2; ++bt) {
      const int row = bt * 16 + nl;
      f32x4 acc = {0.f, 0.f, 0.f, 0.f};
      const f16* xb = &Xl[row * XS + q * 8];
      #pragma unroll
      for (int kt = 0; kt < 8; ++kt)
        acc = __builtin_amdgcn_mfma_f32_16x16x32_f16(wif[kt], *(const half8*)(xb + kt * 32), acc, 0, 0, 0);
      const f16* hb = &Hl[row * HS + q * 8];
      const f16* cb = &Cl[row * HS + q * 8];
      half8 h0 = *(const half8*)hb, h1 = *(const half8*)(hb + 32);
      half8 c0 = *(const half8*)cb, c1 = *(const half8*)(cb + 32);
      acc = __builtin_amdgcn_mfma_f32_16x16x32_f16(wef[0], h0, acc, 0, 0, 0);
      acc = __builtin_amdgcn_mfma_f32_16x16x32_f16(wef[1], h1, acc, 0, 0, 0);
      acc = __builtin_amdgcn_mfma_f32_16x16x32_f16(wef[2], c0, acc, 0, 0, 0);
      acc = __builtin_amdgcn_mfma_f32_16x16x32_f16(wef[3], c1, acc, 0, 0, 0);
      f16x4 uv;
      #pragma unroll
      for (int r = 0; r < 4; ++r) uv[r] = (f16)tanhf_(acc[r] + wib[r]);
      *(f16x4*)(&Ul[row * HS + d0]) = uv;
      if (t > 0) {
        f32x4 aw = {0.f, 0.f, 0.f, 0.f};
        aw = __builtin_amdgcn_mfma_f32_16x16x32_f16(wdf[0], h0, aw, 0, 0, 0);
        aw = __builtin_amdgcn_mfma_f32_16x16x32_f16(wdf[1], h1, aw, 0, 0, 0);
        f16x4 wv;
        #pragma unroll
        for (int r = 0; r < 4; ++r) wv[r] = (f16)(aw[r] + wdb[r]);
        *(f16x4*)(&wmid[((size_t)(b0 + row) * LEN + (t - 1)) * HN + d0]) = wv;
      }
    }
    bar_lds();

    #pragma unroll
    for (int bt = 0; bt < 2; ++bt) {
      const int row = bt * 16 + nl;
      const f16* ub = &Ul[row * HS + q * 8];
      half8 u0 = *(const half8*)ub, u1 = *(const half8*)(ub + 32);
      float ee[16];
      #pragma unroll
      for (int i = 0; i < 4; ++i) {
        f32x4 acc = {0.f, 0.f, 0.f, 0.f};
        acc = __builtin_amdgcn_mfma_f32_16x16x32_f16(vdf[i][0], u0, acc, 0, 0, 0);
        acc = __builtin_amdgcn_mfma_f32_16x16x32_f16(vdf[i][1], u1, acc, 0, 0, 0);
        #pragma unroll
        for (int r = 0; r < 4; ++r)
          ee[i*4+r] = exp2f((acc[r] + vdb[i*4+r]) * 1.44269504f);
      }
      float s = 0.f;
      #pragma unroll
      for (int j = 0; j < 16; ++j) s += ee[j];
      s += __shfl_xor(s, 16, 64);
      s += __shfl_xor(s, 32, 64);
      if (lane < 16) Sred[bt * 64 + w * 16 + lane] = s;
      #pragma unroll
      for (int i = 0; i < 4; ++i) {
        const int k = (w + 4*i) * 16 + q * 4;
        f16x4 xv = *(const f16x4*)(&Xl[row * XS + k]);
        f16x4 pv;
        #pragma unroll
        for (int r = 0; r < 4; ++r) pv[r] = (f16)((float)xv[r] * ee[i*4+r]);
        *(f16x4*)(&Xl[row * XS + k]) = pv;
      }
    }
    bar_lds();

    f16x4 hstash[2], cstash[2];
    #pragma unroll
    for (int bt = 0; bt < 2; ++bt) {
      const int row = bt * 16 + nl;
      f32x4 g[4], gh[4];
      #pragma unroll
      for (int i = 0; i < 4; ++i) {
        g[i]  = (f32x4){0.f, 0.f, 0.f, 0.f};
        gh[i] = (f32x4){0.f, 0.f, 0.f, 0.f};
      }
      const f16* pb = &Xl[row * XS + q * 8];
      #pragma unroll
      for (int kt = 0; kt < 8; ++kt) {
        half8 bv = *(const half8*)(pb + kt * 32);
        #pragma unroll
        for (int i = 0; i < 4; ++i)
          g[i] = __builtin_amdgcn_mfma_f32_16x16x32_f16(whf[i][kt], bv, g[i], 0, 0, 0);
      }
      const f16* hb = &Hl[row * HS + q * 8];
      half8 h0 = *(const half8*)hb, h1 = *(const half8*)(hb + 32);
      #pragma unroll
      for (int i = 0; i < 4; ++i) {
        gh[i] = __builtin_amdgcn_mfma_f32_16x16x32_f16(whhf[i][0], h0, gh[i], 0, 0, 0);
        gh[i] = __builtin_amdgcn_mfma_f32_16x16x32_f16(whhf[i][1], h1, gh[i], 0, 0, 0);
      }
      const float inv = rcp_(Sred[bt*64 + nl]      + Sred[bt*64 + 16 + nl]
                           + Sred[bt*64 + 32 + nl] + Sred[bt*64 + 48 + nl]);
      f16x4 hv, cv;
      #pragma unroll
      for (int r = 0; r < 4; ++r) {
        const float gi = g[0][r] * inv + gh[0][r] + ebs[0  + r];
        const float gf = g[1][r] * inv + gh[1][r] + ebs[4  + r];
        const float gg = g[2][r] * inv + gh[2][r] + ebs[8  + r];
        const float go = g[3][r] * inv + gh[3][r] + ebs[12 + r];
        float c = sigm(gf) * creg[bt][r] + sigm(gi) * tanhf_(gg);
        creg[bt][r] = c;
        const float h = sigm(go) * tanhf_(c);
        hv[r] = (f16)h; cv[r] = (f16)c;
      }
      hstash[bt] = hv; cstash[bt] = cv;
      *(f16x4*)(&mid[((size_t)(b0 + row) * LEN + t) * HN + d0]) = hv;
    }
    bar_lds();
    #pragma unroll
    for (int bt = 0; bt < 2; ++bt) {
      const int row = bt * 16 + nl;
      *(f16x4*)(&Hl[row * HS + d0]) = hstash[bt];
      *(f16x4*)(&Cl[row * HS + d0]) = cstash[bt];
    }
  }

  bar_lds();
  #pragma unroll
  for (int bt = 0; bt < 2; ++bt) {
    const int row = bt * 16 + nl;
    const f16* hb = &Hl[row * HS + q * 8];
    half8 h0 = *(const half8*)hb, h1 = *(const half8*)(hb + 32);
    f32x4 aw = {0.f, 0.f, 0.f, 0.f};
    aw = __builtin_amdgcn_mfma_f32_16x16x32_f16(wdf[0], h0, aw, 0, 0, 0);
    aw = __builtin_amdgcn_mfma_f32_16x16x32_f16(wdf[1], h1, aw, 0, 0, 0);
    f16x4 wv;
    #pragma unroll
    for (int r = 0; r < 4; ++r) wv[r] = (f16)(aw[r] + wdb[r]);
    *(f16x4*)(&wmid[((size_t)(b0 + row) * LEN + (LEN - 1)) * HN + d0]) = wv;
  }
}

// ---------------- decoder v3: wm rows register-resident, tiny LDS ----------
__global__ __launch_bounds__(512) void dec_kernel(
    const f16* __restrict__ mids,     // cols 0..63 at stride MS per (b,t)
    const f16* __restrict__ wms,      // cols 0..63 at stride MS per (b,t)
    const int MS,
    const float* __restrict__ lblp,
    const float* __restrict__ Wd2_w,  // (64,2)
    const float* __restrict__ Vdt_w,  // (1,64)
    const float* __restrict__ Vdt_b,  // (1)
    const float* __restrict__ dWih,   // (4,65)
    const float* __restrict__ dWhh,   // (4,1)
    const float* __restrict__ dbih, const float* __restrict__ dbhh,
    float* __restrict__ out)          // (B,LD)
{
  __shared__ __attribute__((aligned(16))) float qv[DW][HN];
  __shared__ __attribute__((aligned(16))) float vs[HN];
  __shared__ __attribute__((aligned(16))) float ws4[4 * 65];

  const int w    = threadIdx.x >> 6;
  const int lane = threadIdx.x & 63;
  const int b    = blockIdx.x * DW + w;

  if (threadIdx.x < HN)     vs[threadIdx.x]  = Vdt_w[threadIdx.x];
  if (threadIdx.x < 4 * 65) ws4[threadIdx.x] = dWih[threadIdx.x];

  half8 wmr[8];
  if (lane < LEN) {
    const f16* p = wms + ((size_t)b * LEN + lane) * MS;
    #pragma unroll
    for (int k = 0; k < 8; ++k) wmr[k] = *(const half8*)(p + k * 8);
  } else {
    #pragma unroll
    for (int k = 0; k < 8; ++k)
      #pragma unroll
      for (int e = 0; e < 8; ++e) wmr[k][e] = (f16)0.f;
  }
  __syncthreads();

  float macc[4] = {0.f, 0.f, 0.f, 0.f};
  if (lane < LEN) {
    const f16* mrow = mids + ((size_t)b * LEN + lane) * MS;
    #pragma unroll
    for (int k8 = 0; k8 < 8; ++k8) {
      half8 mv = *(const half8*)(mrow + k8 * 8);
      #pragma unroll
      for (int e = 0; e < 8; ++e) {
        const float m = (float)mv[e];
        #pragma unroll
        for (int j = 0; j < 4; ++j) macc[j] += ws4[j * 65 + k8 * 8 + e] * m;
      }
    }
  }

  const float dpin = lblp[b * LEN + (LEN - 1)];
  const float w20 = Wd2_w[2 * lane];
  const float w21 = Wd2_w[2 * lane + 1];
  const float vdtb = Vdt_b[0];
  float wxx[4], whh4[4], bb4[4];
  #pragma unroll
  for (int j = 0; j < 4; ++j) {
    wxx[j]  = dWih[j * 65 + 64];
    whh4[j] = dWhh[j];
    bb4[j]  = dbih[j] + dbhh[j];
  }

  float hi = 0.0f, ci = 0.0f;
  for (int s = 0; s < LDN; ++s) {
    qv[w][lane] = w20 * hi + w21 * ci;

    float p0 = 0.f, p1 = 0.f, p2 = 0.f, p3 = 0.f;
    if (lane < LEN) {
      float acc = 0.f;
      #pragma unroll
      for (int k8 = 0; k8 < 8; ++k8) {
        float4 qa = *(const float4*)&qv[w][k8 * 8];
        float4 qb = *(const float4*)&qv[w][k8 * 8 + 4];
        float4 va = *(const float4*)&vs[k8 * 8];
        float4 vb = *(const float4*)&vs[k8 * 8 + 4];
        half8 wv = wmr[k8];
        acc += tanhf_(qa.x + (float)wv[0]) * va.x
             + tanhf_(qa.y + (float)wv[1]) * va.y
             + tanhf_(qa.z + (float)wv[2]) * va.z
             + tanhf_(qa.w + (float)wv[3]) * va.w
             + tanhf_(qb.x + (float)wv[4]) * vb.x
             + tanhf_(qb.y + (float)wv[5]) * vb.y
             + tanhf_(qb.z + (float)wv[6]) * vb.z
             + tanhf_(qb.w + (float)wv[7]) * vb.w;
      }
      const float score = acc + vdtb;
      p0 = score * macc[0]; p1 = score * macc[1];
      p2 = score * macc[2]; p3 = score * macc[3];
    }
    #pragma unroll
    for (int off = 32; off >= 1; off >>= 1) {
      p0 += __shfl_xor(p0, off, 64);
      p1 += __shfl_xor(p1, off, 64);
      p2 += __shfl_xor(p2, off, 64);
      p3 += __shfl_xor(p3, off, 64);
    }
    const float g0 = p0 + wxx[0] * dpin + bb4[0] + whh4[0] * hi;
    const float g1 = p1 + wxx[1] * dpin + bb4[1] + whh4[1] * hi;
    const float g2 = p2 + wxx[2] * dpin + bb4[2] + whh4[2] * hi;
    const float g3 = p3 + wxx[3] * dpin + bb4[3] + whh4[3] * hi;
    ci = sigm(g1) * ci + sigm(g0) * tanhf_(g2);
    hi = sigm(g3) * tanhf_(ci);
    if (lane == 0) out[b * LDN + s] = hi;
  }
}

extern "C" void kernel_launch(void* const* d_in, const int* in_sizes, int n_in,
                              void* d_out, int out_size, void* d_ws, size_t ws_size,
                              hipStream_t stream) {
  (void)in_sizes; (void)n_in; (void)out_size;
  const float* ipq   = (const float*)d_in[0];
  const float* lblp  = (const float*)d_in[1];
  const float* e_h   = (const float*)d_in[2];
  const float* e_w   = (const float*)d_in[3];
  const float* e_m   = (const float*)d_in[4];
  const float* e_y   = (const float*)d_in[5];
  const float* Wi_w  = (const float*)d_in[6];
  const float* Wi_b  = (const float*)d_in[7];
  const float* We_w  = (const float*)d_in[8];
  const float* Vd_w  = (const float*)d_in[9];
  const float* Vd_b  = (const float*)d_in[10];
  const float* eWih  = (const float*)d_in[11];
  const float* eWhh  = (const float*)d_in[12];
  const float* ebih  = (const float*)d_in[13];
  const float* ebhh  = (const float*)d_in[14];
  const float* Wd_w  = (const float*)d_in[15];
  const float* Wd_b  = (const float*)d_in[16];
  const float* Wd2_w = (const float*)d_in[17];
  const float* Vdt_w = (const float*)d_in[18];
  const float* Vdt_b = (const float*)d_in[19];
  const float* dWih  = (const float*)d_in[20];
  const float* dWhh  = (const float*)d_in[21];
  const float* dbih  = (const float*)d_in[22];
  const float* dbhh  = (const float*)d_in[23];
  const int* itime   = (const int*)d_in[24];
  float* out = (float*)d_out;

  const size_t xpreB = (size_t)BB * LEN * XPS * 2;   // 167.77 MB
  const size_t wcvtB = (size_t)W_TOTAL * 2;          // 254 KB

  if (ws_size >= xpreB + wcvtB) {
    f16* xpre = (f16*)d_ws;
    f16* wcvt = (f16*)((char*)d_ws + xpreB);
    prep_all<<<dim3(PREP_BLOCKS + CONV_BLOCKS), dim3(256), 0, stream>>>(
        ipq, e_h, e_w, e_m, e_y, itime, xpre,
        Wi_w, We_w, Vd_w, eWih, eWhh, Wd_w, wcvt);
    enc_x<<<dim3(ENC_BLOCKS), dim3(512), 0, stream>>>(
        xpre, Wi_b, Vd_b, ebih, ebhh, Wd_b, wcvt, xpre);
    dec_kernel<<<dim3(DEC_BLOCKS), dim3(512), 0, stream>>>(
        xpre, xpre + 64, XPS, lblp, Wd2_w, Vdt_w, Vdt_b,
        dWih, dWhh, dbih, dbhh, out);
  } else {
    const size_t midB = (size_t)BB * LEN * HN * 2;   // 41.94 MB
    f16* mid  = (f16*)d_ws;
    f16* wmid = (f16*)((char*)d_ws + midB);
    f16* wcvt = (f16*)((char*)d_ws + 2 * midB);
    conv_w<<<dim3(CONV_BLOCKS), dim3(256), 0, stream>>>(
        Wi_w, We_w, Vd_w, eWih, eWhh, Wd_w, wcvt);
    enc_fb<<<dim3(ENC_BLOCKS), dim3(256), 0, stream>>>(
        ipq, e_h, e_w, e_m, e_y, Wi_b, Vd_b, ebih, ebhh, Wd_b, wcvt, itime,
        mid, wmid);
    dec_kernel<<<dim3(DEC_BLOCKS), dim3(512), 0, stream>>>(
        mid, wmid, HN, lblp, Wd2_w, Vdt_w, Vdt_b,
        dWih, dWhh, dbih, dbhh, out);
  }
}

// Round 6
// 802.317 us; speedup vs baseline: 1.0999x; 1.0330x over previous
//
#include <hip/hip_runtime.h>

#define BB   8192
#define LEN  40
#define LDN  12
#define PQN  237
#define INN  256
#define HN   64
#define BT   32                 // encoder batches per block (2 MFMA n-tiles)
#define ENC_BLOCKS (BB / BT)    // 256 -> 1 block/CU
#define DW   8                  // decoder batches per block (1 wave each)
#define DEC_BLOCKS (BB / DW)    // 1024
#define XPS  256                // xpre row stride in f16 (power of 2)

typedef unsigned int  u32;
typedef _Float16 f16;
typedef f16  half8 __attribute__((ext_vector_type(8)));
typedef f16  f16x4 __attribute__((ext_vector_type(4)));
typedef float f32x4 __attribute__((ext_vector_type(4)));

#define XS 264   // X/P LDS row stride (f16): reads 2-way max bank aliasing
#define HS 72    // U/H/C LDS row stride (f16): 2-way max

// weight offsets (f16 elements) in converted buffer
#define OFF_WI   0
#define OFF_WE   16384
#define OFF_VD   24576
#define OFF_WIH  40960
#define OFF_WHH  106496
#define OFF_WD   122880
#define W_TOTAL  126976

// LDS-staged embedding tables (f32) for fallback encoder
#define T_H   0
#define T_W   120
#define T_M   144
#define T_Y   196
#define T_TOT 574

#define PREP_BLOCKS (BB * LEN / 32)          // 10240
#define CONV_BLOCKS ((W_TOTAL + 255) / 256)  // 496

__device__ __forceinline__ float rcp_(float x){
#if __has_builtin(__builtin_amdgcn_rcpf)
  return __builtin_amdgcn_rcpf(x);
#else
  return 1.0f / x;
#endif
}
__device__ __forceinline__ float sigm(float x){
  return rcp_(1.0f + exp2f(-1.44269504f * x));
}
// tanh = 1 - 2/(e^{2x}+1); exp2 over/underflow saturates cleanly, no clamp.
__device__ __forceinline__ float tanhf_(float x){
  float e = exp2f(2.88539008f * x);
  return 1.0f - 2.0f * rcp_(e + 1.0f);
}

// lgkm-only barrier: LDS producer->consumer ordering WITHOUT draining vmcnt.
__device__ __forceinline__ void bar_lds(){
  asm volatile("s_waitcnt lgkmcnt(0)" ::: "memory");
  __builtin_amdgcn_s_barrier();
  asm volatile("" ::: "memory");
}

// ---------------- weight f32 -> f16 conversion (fallback path) -------------
__global__ __launch_bounds__(256) void conv_w(
    const float* __restrict__ Wi, const float* __restrict__ We,
    const float* __restrict__ Vd, const float* __restrict__ Wih,
    const float* __restrict__ Whh, const float* __restrict__ Wd,
    f16* __restrict__ dst)
{
  int i = blockIdx.x * 256 + threadIdx.x;
  if (i >= W_TOTAL) return;
  float v;
  if      (i < OFF_WE)  v = Wi [i - OFF_WI ];
  else if (i < OFF_VD)  v = We [i - OFF_WE ];
  else if (i < OFF_WIH) v = Vd [i - OFF_VD ];
  else if (i < OFF_WHH) v = Wih[i - OFF_WIH];
  else if (i < OFF_WD)  v = Whh[i - OFF_WHH];
  else                  v = Wd [i - OFF_WD ];
  dst[i] = (f16)v;
}

// ---------------- prep_all: X materialization + fused weight convert -------
__global__ __launch_bounds__(256) void prep_all(
    const float* __restrict__ ipq,
    const float* __restrict__ e_h, const float* __restrict__ e_w,
    const float* __restrict__ e_m, const float* __restrict__ e_y,
    const int*  __restrict__ itime,
    f16* __restrict__ xpre,
    const float* __restrict__ Wi, const float* __restrict__ We,
    const float* __restrict__ Vd, const float* __restrict__ Wih,
    const float* __restrict__ Whh, const float* __restrict__ Wd,
    f16* __restrict__ wdst)
{
  if (blockIdx.x >= PREP_BLOCKS) {
    int i = (blockIdx.x - PREP_BLOCKS) * 256 + threadIdx.x;
    if (i >= W_TOTAL) return;
    float v;
    if      (i < OFF_WE)  v = Wi [i - OFF_WI ];
    else if (i < OFF_VD)  v = We [i - OFF_WE ];
    else if (i < OFF_WIH) v = Vd [i - OFF_VD ];
    else if (i < OFF_WHH) v = Wih[i - OFF_WIH];
    else if (i < OFF_WD)  v = Whh[i - OFF_WHH];
    else                  v = Wd [i - OFF_WD ];
    wdst[i] = (f16)v;
    return;
  }
  const int wv = threadIdx.x >> 6, l = threadIdx.x & 63;
  const size_t row0 = (size_t)blockIdx.x * 32 + (size_t)wv * 8;
  int4 itv[8];
  #pragma unroll
  for (int r = 0; r < 8; ++r)
    itv[r] = *(const int4*)(itime + (row0 + r) * 4);
  #pragma unroll
  for (int r = 0; r < 8; ++r) {
    const size_t row = row0 + r;               // = b*LEN + t
    const float* src = ipq + row * PQN;
    f16* dst = xpre + row * XPS;
    #pragma unroll
    for (int k = 0; k < 3; ++k) {
      const int c = k * 64 + l;
      dst[c] = (f16)src[c];
    }
    {
      const int c = 192 + l;
      float v;
      if (c < PQN) v = src[c];
      else {
        const int o = c - PQN;
        if      (o < 5 ) v = e_h[itv[r].x * 5 + o];
        else if (o < 8 ) v = e_w[itv[r].y * 3 + (o - 5)];
        else if (o < 12) v = e_m[itv[r].z * 4 + (o - 8)];
        else             v = e_y[itv[r].w * 7 + (o - 12)];
      }
      dst[c] = (f16)v;
    }
  }
}

// ---------------- encoder v5: 2 waves/SIMD, zero-spill weight split --------
// (unchanged from round 5 -- proven)
__global__ __launch_bounds__(512, 2) void enc_x(
    const f16* __restrict__ xpre,
    const float* __restrict__ Wi_b,   // (64)
    const float* __restrict__ Vd_b,   // (256)
    const float* __restrict__ ebih, const float* __restrict__ ebhh, // (256)
    const float* __restrict__ Wd_b,   // (64)
    const f16*  __restrict__ wAll,
    f16* __restrict__ xout)           // == xpre (overlay)
{
  __shared__ __attribute__((aligned(16))) f16 Xl[BT * XS];       // 16.9 KB
  __shared__ __attribute__((aligned(16))) f16 Ul[BT * HS];       //  4.6 KB
  __shared__ __attribute__((aligned(16))) f16 Hl[BT * HS];       //  4.6 KB
  __shared__ __attribute__((aligned(16))) f16 Cl[BT * HS];       //  4.6 KB
  __shared__ float Sred[2 * 64];                                 //  0.5 KB
  __shared__ __attribute__((aligned(16))) f16 WiL[4 * 8 * 64 * 8];  // 32 KB
  __shared__ __attribute__((aligned(16))) f16 WeL[4 * 4 * 64 * 8];  // 16 KB
  __shared__ __attribute__((aligned(16))) f16 VdL[16 * 2 * 64 * 8]; // 32 KB
  __shared__ __attribute__((aligned(16))) f16 WhL[16 * 2 * 64 * 8]; // 32 KB
  __shared__ __attribute__((aligned(16))) f16 WdL[4 * 2 * 64 * 8];  //  8 KB
  __shared__ float VdbL[256];
  __shared__ float EbsL[256];

  const int tid  = threadIdx.x;
  const int w    = tid >> 6;
  const int lane = tid & 63;
  const int nl   = lane & 15;
  const int q    = lane >> 4;
  const int wsub = w & 3;
  const int bt   = w >> 2;
  const int b0   = blockIdx.x * BT;
  const int d0   = wsub * 16 + q * 4;
  const int row  = bt * 16 + nl;     // batch row (n-dim) this wave's MFMA

  // staging map (512 thr): row r0(+16), 16B chunk off
  const int r0  = tid >> 5;          // 0..15
  const int off = tid & 31;
  const f16* gb0 = xpre + ((size_t)(b0 + r0     ) * LEN) * XPS + off * 8;
  const f16* gb1 = xpre + ((size_t)(b0 + r0 + 16) * LEN) * XPS + off * 8;
  const u32 lwa = (u32)(r0 * XS + off * 8);
  const u32 lwb = (u32)((r0 + 16) * XS + off * 8);

  // mid streaming map: one f16x4 per thread (32 rows x 64 cols)
  const int orow = tid >> 4;
  const int oc4  = (tid & 15) * 4;

  // ---- issue t=0 staging loads first ----
  half8 sr0 = *(const half8*)gb0;
  half8 sr1 = *(const half8*)gb1;

  // ---- register weights: Wih slices only (128 AGPR exactly) ----
  half8 whf[4][8];
  #pragma unroll
  for (int i = 0; i < 4; ++i) {
    const f16* ph = wAll + OFF_WIH + ((wsub + 4*i) * 16 + nl) * 256 + q * 8;
    #pragma unroll
    for (int kt = 0; kt < 8; ++kt) whf[i][kt] = *(const half8*)(ph + kt * 32);
  }
  float wib[4], wdb[4];
  #pragma unroll
  for (int r = 0; r < 4; ++r) { wib[r] = Wi_b[d0 + r]; wdb[r] = Wd_b[d0 + r]; }

  // ---- LDS weights: [tile][kt][lane] fragment layout ----
  for (int s = tid; s < 4 * 8 * 64; s += 512) {     // Wi: 4 tiles, kt=8
    const int tile = s >> 9, kt = (s >> 6) & 7, ln = s & 63;
    *(half8*)(&WiL[(size_t)s * 8]) = *(const half8*)(
        wAll + OFF_WI + (tile * 16 + (ln & 15)) * 256 + (ln >> 4) * 8 + kt * 32);
  }
  for (int s = tid; s < 4 * 4 * 64; s += 512) {     // We: 4 tiles, j=4
    const int tile = s >> 8, j = (s >> 6) & 3, ln = s & 63;
    *(half8*)(&WeL[(size_t)s * 8]) = *(const half8*)(
        wAll + OFF_WE + (tile * 16 + (ln & 15)) * 128 + (ln >> 4) * 8 + j * 32);
  }
  for (int s = tid; s < 16 * 2 * 64; s += 512) {    // Vd: 16 tiles, kt=2
    const int tile = s >> 7, kt = (s >> 6) & 1, ln = s & 63;
    *(half8*)(&VdL[(size_t)s * 8]) = *(const half8*)(
        wAll + OFF_VD + (tile * 16 + (ln & 15)) * 64 + (ln >> 4) * 8 + kt * 32);
  }
  for (int s = tid; s < 16 * 2 * 64; s += 512) {    // Whh: 16 tiles, kt=2
    const int tile = s >> 7, kt = (s >> 6) & 1, ln = s & 63;
    *(half8*)(&WhL[(size_t)s * 8]) = *(const half8*)(
        wAll + OFF_WHH + (tile * 16 + (ln & 15)) * 64 + (ln >> 4) * 8 + kt * 32);
  }
  for (int s = tid; s < 4 * 2 * 64; s += 512) {     // Wd: 4 tiles, kt=2
    const int tile = s >> 7, kt = (s >> 6) & 1, ln = s & 63;
    *(half8*)(&WdL[(size_t)s * 8]) = *(const half8*)(
        wAll + OFF_WD + (tile * 16 + (ln & 15)) * 64 + (ln >> 4) * 8 + kt * 32);
  }
  if (tid < 256) {
    VdbL[tid] = Vd_b[tid];
    EbsL[tid] = ebih[tid] + ebhh[tid];
  }
  for (int i = tid; i < BT * HS; i += 512) {
    Hl[i] = (f16)0.f; Cl[i] = (f16)0.f;
  }
  float creg[4] = {0.f, 0.f, 0.f, 0.f};
  bar_lds();

  for (int t = 0; t < LEN; ++t) {
    // ---- top: staged regs -> Xl; reissue prefetch for t+1 ----
    *(half8*)(&Xl[lwa]) = sr0;
    *(half8*)(&Xl[lwb]) = sr1;
    if (t + 1 < LEN) {
      sr0 = *(const half8*)(gb0 + (size_t)(t + 1) * XPS);
      sr1 = *(const half8*)(gb1 + (size_t)(t + 1) * XPS);
    }
    bar_lds();   // A: Xl ready; Hl/Cl(t-1) ready (written after D(t-1))

    // ---- phase 2: U = tanh(Wi@X + We@[H;C] + b); wm(t-1) direct store ----
    {
      // split accumulator chains: depth 6 each instead of 12
      f32x4 a0 = {0.f, 0.f, 0.f, 0.f}, a1 = {0.f, 0.f, 0.f, 0.f};
      const f16* xb = &Xl[row * XS + q * 8];
      #pragma unroll
      for (int kt = 0; kt < 4; ++kt)
        a0 = __builtin_amdgcn_mfma_f32_16x16x32_f16(
            *(const half8*)(&WiL[((wsub * 8 + kt) * 64 + lane) * 8]),
            *(const half8*)(xb + kt * 32), a0, 0, 0, 0);
      #pragma unroll
      for (int kt = 4; kt < 8; ++kt)
        a1 = __builtin_amdgcn_mfma_f32_16x16x32_f16(
            *(const half8*)(&WiL[((wsub * 8 + kt) * 64 + lane) * 8]),
            *(const half8*)(xb + kt * 32), a1, 0, 0, 0);
      const f16* hb = &Hl[row * HS + q * 8];
      const f16* cb = &Cl[row * HS + q * 8];
      half8 h0 = *(const half8*)hb, h1 = *(const half8*)(hb + 32);
      half8 c0 = *(const half8*)cb, c1 = *(const half8*)(cb + 32);
      a0 = __builtin_amdgcn_mfma_f32_16x16x32_f16(
          *(const half8*)(&WeL[((wsub * 4 + 0) * 64 + lane) * 8]), h0, a0, 0, 0, 0);
      a1 = __builtin_amdgcn_mfma_f32_16x16x32_f16(
          *(const half8*)(&WeL[((wsub * 4 + 1) * 64 + lane) * 8]), h1, a1, 0, 0, 0);
      a0 = __builtin_amdgcn_mfma_f32_16x16x32_f16(
          *(const half8*)(&WeL[((wsub * 4 + 2) * 64 + lane) * 8]), c0, a0, 0, 0, 0);
      a1 = __builtin_amdgcn_mfma_f32_16x16x32_f16(
          *(const half8*)(&WeL[((wsub * 4 + 3) * 64 + lane) * 8]), c1, a1, 0, 0, 0);
      f16x4 uv;
      #pragma unroll
      for (int r = 0; r < 4; ++r) uv[r] = (f16)tanhf_(a0[r] + a1[r] + wib[r]);
      *(f16x4*)(&Ul[row * HS + d0]) = uv;
      if (t > 0) {   // wm(t-1): direct scattered 8B store (proven in r2)
        f32x4 aw = {0.f, 0.f, 0.f, 0.f};
        aw = __builtin_amdgcn_mfma_f32_16x16x32_f16(
            *(const half8*)(&WdL[((wsub * 2 + 0) * 64 + lane) * 8]), h0, aw, 0, 0, 0);
        aw = __builtin_amdgcn_mfma_f32_16x16x32_f16(
            *(const half8*)(&WdL[((wsub * 2 + 1) * 64 + lane) * 8]), h1, aw, 0, 0, 0);
        f16x4 wv;
        #pragma unroll
        for (int r = 0; r < 4; ++r) wv[r] = (f16)(aw[r] + wdb[r]);
        *(f16x4*)(&xout[((size_t)(b0 + row) * LEN + (t - 1)) * XPS + 64 + d0]) = wv;
      }
    }
    bar_lds();   // B: Ul ready

    // ---- phase 3: stream mid(t-1); ee = exp(Vd@U+b); P = X*ee ----
    if (t > 0) {   // coalesced f16x4: 16 threads -> 128B contiguous
      f16x4 hv4 = *(const f16x4*)(&Hl[orow * HS + oc4]);
      *(f16x4*)(&xout[((size_t)(b0 + orow) * LEN + (t - 1)) * XPS + oc4]) = hv4;
    }
    {
      const f16* ub = &Ul[row * HS + q * 8];
      half8 u0 = *(const half8*)ub, u1 = *(const half8*)(ub + 32);
      float s = 0.f;
      #pragma unroll
      for (int i = 0; i < 4; ++i) {
        const int tile = wsub + 4 * i;
        f32x4 acc = {0.f, 0.f, 0.f, 0.f};
        acc = __builtin_amdgcn_mfma_f32_16x16x32_f16(
            *(const half8*)(&VdL[((tile * 2 + 0) * 64 + lane) * 8]), u0, acc, 0, 0, 0);
        acc = __builtin_amdgcn_mfma_f32_16x16x32_f16(
            *(const half8*)(&VdL[((tile * 2 + 1) * 64 + lane) * 8]), u1, acc, 0, 0, 0);
        const int k = tile * 16 + q * 4;
        f16x4 xv = *(const f16x4*)(&Xl[row * XS + k]);
        f16x4 pv;
        float ee[4];
        #pragma unroll
        for (int r = 0; r < 4; ++r) {
          ee[r] = exp2f((acc[r] + VdbL[k + r]) * 1.44269504f);
          s += ee[r];
          pv[r] = (f16)((float)xv[r] * ee[r]);
        }
        *(f16x4*)(&Xl[row * XS + k]) = pv;   // unnormalized P in place
      }
      s += __shfl_xor(s, 16, 64);
      s += __shfl_xor(s, 32, 64);
      if (lane < 16) Sred[bt * 64 + wsub * 16 + lane] = s;
    }
    bar_lds();   // C: P + Sred ready

    // ---- phase 4: gates; LSTM; stash; barrier D; H/C writes ----
    f16x4 hv, cv;
    {
      f32x4 g[4], gh[4];
      #pragma unroll
      for (int i = 0; i < 4; ++i) {
        g[i]  = (f32x4){0.f, 0.f, 0.f, 0.f};
        gh[i] = (f32x4){0.f, 0.f, 0.f, 0.f};
      }
      const f16* pb = &Xl[row * XS + q * 8];
      #pragma unroll
      for (int kt = 0; kt < 8; ++kt) {
        half8 bv = *(const half8*)(pb + kt * 32);
        #pragma unroll
        for (int i = 0; i < 4; ++i)
          g[i] = __builtin_amdgcn_mfma_f32_16x16x32_f16(whf[i][kt], bv, g[i], 0, 0, 0);
      }
      const f16* hb = &Hl[row * HS + q * 8];
      half8 h0 = *(const half8*)hb, h1 = *(const half8*)(hb + 32);
      #pragma unroll
      for (int i = 0; i < 4; ++i) {
        const int tile = wsub + 4 * i;
        gh[i] = __builtin_amdgcn_mfma_f32_16x16x32_f16(
            *(const half8*)(&WhL[((tile * 2 + 0) * 64 + lane) * 8]), h0, gh[i], 0, 0, 0);
        gh[i] = __builtin_amdgcn_mfma_f32_16x16x32_f16(
            *(const half8*)(&WhL[((tile * 2 + 1) * 64 + lane) * 8]), h1, gh[i], 0, 0, 0);
      }
      const float inv = rcp_(Sred[bt*64 + nl]      + Sred[bt*64 + 16 + nl]
                           + Sred[bt*64 + 32 + nl] + Sred[bt*64 + 48 + nl]);
      #pragma unroll
      for (int r = 0; r < 4; ++r) {
        const float gi = g[0][r] * inv + gh[0][r] + EbsL[0   + d0 + r];
        const float gf = g[1][r] * inv + gh[1][r] + EbsL[64  + d0 + r];
        const float gg = g[2][r] * inv + gh[2][r] + EbsL[128 + d0 + r];
        const float go = g[3][r] * inv + gh[3][r] + EbsL[192 + d0 + r];
        float c = sigm(gf) * creg[r] + sigm(gi) * tanhf_(gg);
        creg[r] = c;
        const float h = sigm(go) * tanhf_(c);
        hv[r] = (f16)h; cv[r] = (f16)c;
      }
    }
    bar_lds();   // D: all waves done reading P/H -> safe to overwrite H/C
    *(f16x4*)(&Hl[row * HS + d0]) = hv;
    *(f16x4*)(&Cl[row * HS + d0]) = cv;
  }

  // ---- epilogue: wm(LEN-1) + stream final mid (Hl = H_{LEN-1}) ----
  bar_lds();
  {
    const f16* hb = &Hl[row * HS + q * 8];
    half8 h0 = *(const half8*)hb, h1 = *(const half8*)(hb + 32);
    f32x4 aw = {0.f, 0.f, 0.f, 0.f};
    aw = __builtin_amdgcn_mfma_f32_16x16x32_f16(
        *(const half8*)(&WdL[((wsub * 2 + 0) * 64 + lane) * 8]), h0, aw, 0, 0, 0);
    aw = __builtin_amdgcn_mfma_f32_16x16x32_f16(
        *(const half8*)(&WdL[((wsub * 2 + 1) * 64 + lane) * 8]), h1, aw, 0, 0, 0);
    f16x4 wv;
    #pragma unroll
    for (int r = 0; r < 4; ++r) wv[r] = (f16)(aw[r] + wdb[r]);
    *(f16x4*)(&xout[((size_t)(b0 + row) * LEN + (LEN - 1)) * XPS + 64 + d0]) = wv;
    f16x4 hv4 = *(const f16x4*)(&Hl[orow * HS + oc4]);
    *(f16x4*)(&xout[((size_t)(b0 + orow) * LEN + (LEN - 1)) * XPS + oc4]) = hv4;
  }
}

// ---------------- fallback encoder (round-2, proven): used if ws small -----
__global__ __launch_bounds__(256, 1) void enc_fb(
    const float* __restrict__ ipq,
    const float* __restrict__ e_h, const float* __restrict__ e_w,
    const float* __restrict__ e_m, const float* __restrict__ e_y,
    const float* __restrict__ Wi_b, const float* __restrict__ Vd_b,
    const float* __restrict__ ebih, const float* __restrict__ ebhh,
    const float* __restrict__ Wd_b, const f16* __restrict__ wAll,
    const int*  __restrict__ itime,
    f16* __restrict__ mid, f16* __restrict__ wmid)
{
  __shared__ __attribute__((aligned(16))) f16 Xl[BT * XS];
  __shared__ __attribute__((aligned(16))) f16 Ul[BT * HS];
  __shared__ __attribute__((aligned(16))) f16 Hl[BT * HS];
  __shared__ __attribute__((aligned(16))) f16 Cl[BT * HS];
  __shared__ float Sred[2 * 64];
  __shared__ float Tl[T_TOT];

  const int tid  = threadIdx.x;
  const int w    = tid >> 6;
  const int lane = tid & 63;
  const int nl   = lane & 15;
  const int q    = lane >> 4;
  const int b0   = blockIdx.x * BT;
  const int d0   = w * 16 + q * 4;

  const u32* pptr;
  int pstr, tstr, tbase = 0, twid = 0, tsub = 0;
  if (tid < PQN) {
    pptr = (const u32*)ipq + tid; pstr = LEN * PQN; tstr = PQN;
  } else {
    const int o = tid - PQN; int sel;
    if      (o < 5 ) { sel = 0; tbase = T_H; twid = 5; tsub = o;      }
    else if (o < 8 ) { sel = 1; tbase = T_W; twid = 3; tsub = o - 5;  }
    else if (o < 12) { sel = 2; tbase = T_M; twid = 4; tsub = o - 8;  }
    else             { sel = 3; tbase = T_Y; twid = 7; tsub = o - 12; }
    pptr = (const u32*)itime + sel; pstr = LEN * 4; tstr = 4;
  }
  pptr += (size_t)b0 * pstr;

  u32 pf[BT];
  #pragma unroll
  for (int bb = 0; bb < BT; ++bb) pf[bb] = pptr[(size_t)bb * pstr];

  half8 wif[8], wef[4], vdf[4][2], whf[4][8], whhf[4][2], wdf[2];
  {
    const f16* pw = wAll + OFF_WI + (w * 16 + nl) * 256 + q * 8;
    #pragma unroll
    for (int kt = 0; kt < 8; ++kt) wif[kt] = *(const half8*)(pw + kt * 32);
    const f16* pe = wAll + OFF_WE + (w * 16 + nl) * 128 + q * 8;
    #pragma unroll
    for (int kt = 0; kt < 4; ++kt) wef[kt] = *(const half8*)(pe + kt * 32);
    #pragma unroll
    for (int i = 0; i < 4; ++i) {
      const f16* pv = wAll + OFF_VD + ((w + 4*i) * 16 + nl) * 64 + q * 8;
      #pragma unroll
      for (int kt = 0; kt < 2; ++kt) vdf[i][kt] = *(const half8*)(pv + kt * 32);
      const f16* ph = wAll + OFF_WIH + ((w + 4*i) * 16 + nl) * 256 + q * 8;
      #pragma unroll
      for (int kt = 0; kt < 8; ++kt) whf[i][kt] = *(const half8*)(ph + kt * 32);
      const f16* pq = wAll + OFF_WHH + ((w + 4*i) * 16 + nl) * 64 + q * 8;
      #pragma unroll
      for (int kt = 0; kt < 2; ++kt) whhf[i][kt] = *(const half8*)(pq + kt * 32);
    }
    const f16* pd = wAll + OFF_WD + (w * 16 + nl) * 64 + q * 8;
    #pragma unroll
    for (int kt = 0; kt < 2; ++kt) wdf[kt] = *(const half8*)(pd + kt * 32);
  }

  float wib[4], vdb[16], ebs[16], wdb[4];
  #pragma unroll
  for (int r = 0; r < 4; ++r) { wib[r] = Wi_b[d0 + r]; wdb[r] = Wd_b[d0 + r]; }
  #pragma unroll
  for (int i = 0; i < 4; ++i)
    #pragma unroll
    for (int r = 0; r < 4; ++r) {
      vdb[i*4+r] = Vd_b[(w + 4*i) * 16 + q * 4 + r];
      ebs[i*4+r] = ebih[i * 64 + d0 + r] + ebhh[i * 64 + d0 + r];
    }

  for (int i = tid; i < BT * HS; i += 256) { Hl[i] = (f16)0.f; Cl[i] = (f16)0.f; }
  for (int i = tid; i < T_TOT; i += 256) {
    float v;
    if      (i < T_W) v = e_h[i];
    else if (i < T_M) v = e_w[i - T_W];
    else if (i < T_Y) v = e_m[i - T_M];
    else              v = e_y[i - T_Y];
    Tl[i] = v;
  }
  float creg[2][4];
  #pragma unroll
  for (int bt = 0; bt < 2; ++bt)
    #pragma unroll
    for (int r = 0; r < 4; ++r) creg[bt][r] = 0.f;
  bar_lds();

  for (int t = 0; t < LEN; ++t) {
    #pragma unroll
    for (int bb = 0; bb < BT; ++bb) {
      float v;
      if (tid < PQN) v = __uint_as_float(pf[bb]);
      else           v = Tl[tbase + (int)pf[bb] * twid + tsub];
      Xl[bb * XS + tid] = (f16)v;
    }
    if (t + 1 < LEN) {
      const u32* pp = pptr + (size_t)(t + 1) * tstr;
      #pragma unroll
      for (int bb = 0; bb < BT; ++bb) pf[bb] = pp[(size_t)bb * pstr];
    }
    bar_lds();

    #pragma unroll
    for (int bt = 0; bt < 2; ++bt) {
      const int row = bt * 16 + nl;
      f32x4 acc = {0.f, 0.f, 0.f, 0.f};
      const f16* xb = &Xl[row * XS + q * 8];
      #pragma unroll
      for (int kt = 0; kt < 8; ++kt)
        acc = __builtin_amdgcn_mfma_f32_16x16x32_f16(wif[kt], *(const half8*)(xb + kt * 32), acc, 0, 0, 0);
      const f16* hb = &Hl[row * HS + q * 8];
      const f16* cb = &Cl[row * HS + q * 8];
      half8 h0 = *(const half8*)hb, h1 = *(const half8*)(hb + 32);
      half8 c0 = *(const half8*)cb, c1 = *(const half8*)(cb + 32);
      acc = __builtin_amdgcn_mfma_f32_16x16x32_f16(wef[0], h0, acc, 0, 0, 0);
      acc = __builtin_amdgcn_mfma_f32_16x16x32_f16(wef[1], h1, acc, 0, 0, 0);
      acc = __builtin_amdgcn_mfma_f32_16x16x32_f16(wef[2], c0, acc, 0, 0, 0);
      acc = __builtin_amdgcn_mfma_f32_16x16x32_f16(wef[3], c1, acc, 0, 0, 0);
      f16x4 uv;
      #pragma unroll
      for (int r = 0; r < 4; ++r) uv[r] = (f16)tanhf_(acc[r] + wib[r]);
      *(f16x4*)(&Ul[row * HS + d0]) = uv;
      if (t > 0) {
        f32x4 aw = {0.f, 0.f, 0.f, 0.f};
        aw = __builtin_amdgcn_mfma_f32_16x16x32_f16(wdf[0], h0, aw, 0, 0, 0);
        aw = __builtin_amdgcn_mfma_f32_16x16x32_f16(wdf[1], h1, aw, 0, 0, 0);
        f16x4 wv;
        #pragma unroll
        for (int r = 0; r < 4; ++r) wv[r] = (f16)(aw[r] + wdb[r]);
        *(f16x4*)(&wmid[((size_t)(b0 + row) * LEN + (t - 1)) * HN + d0]) = wv;
      }
    }
    bar_lds();

    #pragma unroll
    for (int bt = 0; bt < 2; ++bt) {
      const int row = bt * 16 + nl;
      const f16* ub = &Ul[row * HS + q * 8];
      half8 u0 = *(const half8*)ub, u1 = *(const half8*)(ub + 32);
      float ee[16];
      #pragma unroll
      for (int i = 0; i < 4; ++i) {
        f32x4 acc = {0.f, 0.f, 0.f, 0.f};
        acc = __builtin_amdgcn_mfma_f32_16x16x32_f16(vdf[i][0], u0, acc, 0, 0, 0);
        acc = __builtin_amdgcn_mfma_f32_16x16x32_f16(vdf[i][1], u1, acc, 0, 0, 0);
        #pragma unroll
        for (int r = 0; r < 4; ++r)
          ee[i*4+r] = exp2f((acc[r] + vdb[i*4+r]) * 1.44269504f);
      }
      float s = 0.f;
      #pragma unroll
      for (int j = 0; j < 16; ++j) s += ee[j];
      s += __shfl_xor(s, 16, 64);
      s += __shfl_xor(s, 32, 64);
      if (lane < 16) Sred[bt * 64 + w * 16 + lane] = s;
      #pragma unroll
      for (int i = 0; i < 4; ++i) {
        const int k = (w + 4*i) * 16 + q * 4;
        f16x4 xv = *(const f16x4*)(&Xl[row * XS + k]);
        f16x4 pv;
        #pragma unroll
        for (int r = 0; r < 4; ++r) pv[r] = (f16)((float)xv[r] * ee[i*4+r]);
        *(f16x4*)(&Xl[row * XS + k]) = pv;
      }
    }
    bar_lds();

    f16x4 hstash[2], cstash[2];
    #pragma unroll
    for (int bt = 0; bt < 2; ++bt) {
      const int row = bt * 16 + nl;
      f32x4 g[4], gh[4];
      #pragma unroll
      for (int i = 0; i < 4; ++i) {
        g[i]  = (f32x4){0.f, 0.f, 0.f, 0.f};
        gh[i] = (f32x4){0.f, 0.f, 0.f, 0.f};
      }
      const f16* pb = &Xl[row * XS + q * 8];
      #pragma unroll
      for (int kt = 0; kt < 8; ++kt) {
        half8 bv = *(const half8*)(pb + kt * 32);
        #pragma unroll
        for (int i = 0; i < 4; ++i)
          g[i] = __builtin_amdgcn_mfma_f32_16x16x32_f16(whf[i][kt], bv, g[i], 0, 0, 0);
      }
      const f16* hb = &Hl[row * HS + q * 8];
      half8 h0 = *(const half8*)hb, h1 = *(const half8*)(hb + 32);
      #pragma unroll
      for (int i = 0; i < 4; ++i) {
        gh[i] = __builtin_amdgcn_mfma_f32_16x16x32_f16(whhf[i][0], h0, gh[i], 0, 0, 0);
        gh[i] = __builtin_amdgcn_mfma_f32_16x16x32_f16(whhf[i][1], h1, gh[i], 0, 0, 0);
      }
      const float inv = rcp_(Sred[bt*64 + nl]      + Sred[bt*64 + 16 + nl]
                           + Sred[bt*64 + 32 + nl] + Sred[bt*64 + 48 + nl]);
      f16x4 hv, cv;
      #pragma unroll
      for (int r = 0; r < 4; ++r) {
        const float gi = g[0][r] * inv + gh[0][r] + ebs[0  + r];
        const float gf = g[1][r] * inv + gh[1][r] + ebs[4  + r];
        const float gg = g[2][r] * inv + gh[2][r] + ebs[8  + r];
        const float go = g[3][r] * inv + gh[3][r] + ebs[12 + r];
        float c = sigm(gf) * creg[bt][r] + sigm(gi) * tanhf_(gg);
        creg[bt][r] = c;
        const float h = sigm(go) * tanhf_(c);
        hv[r] = (f16)h; cv[r] = (f16)c;
      }
      hstash[bt] = hv; cstash[bt] = cv;
      *(f16x4*)(&mid[((size_t)(b0 + row) * LEN + t) * HN + d0]) = hv;
    }
    bar_lds();
    #pragma unroll
    for (int bt = 0; bt < 2; ++bt) {
      const int row = bt * 16 + nl;
      *(f16x4*)(&Hl[row * HS + d0]) = hstash[bt];
      *(f16x4*)(&Cl[row * HS + d0]) = cstash[bt];
    }
  }

  bar_lds();
  #pragma unroll
  for (int bt = 0; bt < 2; ++bt) {
    const int row = bt * 16 + nl;
    const f16* hb = &Hl[row * HS + q * 8];
    half8 h0 = *(const half8*)hb, h1 = *(const half8*)(hb + 32);
    f32x4 aw = {0.f, 0.f, 0.f, 0.f};
    aw = __builtin_amdgcn_mfma_f32_16x16x32_f16(wdf[0], h0, aw, 0, 0, 0);
    aw = __builtin_amdgcn_mfma_f32_16x16x32_f16(wdf[1], h1, aw, 0, 0, 0);
    f16x4 wv;
    #pragma unroll
    for (int r = 0; r < 4; ++r) wv[r] = (f16)(aw[r] + wdb[r]);
    *(f16x4*)(&wmid[((size_t)(b0 + row) * LEN + (LEN - 1)) * HN + d0]) = wv;
  }
}

// ---------------- decoder v4: lane = d, full 64-lane utilization -----------
// gates_j = sum_t score_t*M4[t][j], score_t = vdtb + sum_d v_d*tanh(q_d+wm[t][d])
// Re-associate: lane d accumulates a_j = sum_t v*tanh(q+wm[t][d])*M4[t][j],
// wave-reduce once.  q_d = w20_d*h + w21_d*c from lane-uniform h,c -> no qv
// LDS round-trip.  vdtb folds in via SM4[j] = sum_t M4[t][j].
// tanh/lane/step: 64 -> 40; idle lanes: 24 -> 0.
__global__ __launch_bounds__(512) void dec_kernel(
    const f16* __restrict__ mids,     // cols 0..63 at stride MS per (b,t)
    const f16* __restrict__ wms,      // cols 0..63 at stride MS per (b,t)
    const int MS,
    const float* __restrict__ lblp,
    const float* __restrict__ Wd2_w,  // (64,2)
    const float* __restrict__ Vdt_w,  // (1,64)
    const float* __restrict__ Vdt_b,  // (1)
    const float* __restrict__ dWih,   // (4,65)
    const float* __restrict__ dWhh,   // (4,1)
    const float* __restrict__ dbih, const float* __restrict__ dbhh,
    float* __restrict__ out)          // (B,LD)
{
  __shared__ __attribute__((aligned(16))) float M4L[DW][LEN][4];  // 5.1 KB
  __shared__ __attribute__((aligned(16))) float ws4[4 * 65];

  const int w    = threadIdx.x >> 6;
  const int lane = threadIdx.x & 63;
  const int b    = blockIdx.x * DW + w;

  // wm column d=lane over all t -> f32 registers.  At fixed t the wave reads
  // wm[t][0..63] = 128 contiguous bytes -> coalesced.
  float wcol[LEN];
  #pragma unroll
  for (int t = 0; t < LEN; ++t)
    wcol[t] = (float)wms[((size_t)b * LEN + t) * MS + lane];

  if (threadIdx.x < 4 * 65) ws4[threadIdx.x] = dWih[threadIdx.x];
  __syncthreads();   // ws4 visible to all waves

  // M4 precompute: lane = t (40 active)
  float macc[4] = {0.f, 0.f, 0.f, 0.f};
  if (lane < LEN) {
    const f16* mrow = mids + ((size_t)b * LEN + lane) * MS;
    #pragma unroll
    for (int k8 = 0; k8 < 8; ++k8) {
      half8 mv = *(const half8*)(mrow + k8 * 8);
      #pragma unroll
      for (int e = 0; e < 8; ++e) {
        const float m = (float)mv[e];
        #pragma unroll
        for (int j = 0; j < 4; ++j) macc[j] += ws4[j * 65 + k8 * 8 + e] * m;
      }
    }
  }
  // SM4[j] = sum_t M4[t][j] (lanes >= LEN hold 0)
  float sm4[4];
  #pragma unroll
  for (int j = 0; j < 4; ++j) {
    float p = macc[j];
    #pragma unroll
    for (int off = 32; off >= 1; off >>= 1) p += __shfl_xor(p, off, 64);
    sm4[j] = p;
  }
  if (lane < LEN) {
    M4L[w][lane][0] = macc[0]; M4L[w][lane][1] = macc[1];
    M4L[w][lane][2] = macc[2]; M4L[w][lane][3] = macc[3];
  }
  // M4L[w] written & read by the SAME wave -> compiler lgkmcnt handles RAW.

  const float dpin = lblp[b * LEN + (LEN - 1)];
  const float w20  = Wd2_w[2 * lane];
  const float w21  = Wd2_w[2 * lane + 1];
  const float v    = Vdt_w[lane];
  const float vdtb = Vdt_b[0];
  float cj[4], whh4[4];
  #pragma unroll
  for (int j = 0; j < 4; ++j) {
    whh4[j] = dWhh[j];
    cj[j] = dWih[j * 65 + 64] * dpin + dbih[j] + dbhh[j] + vdtb * sm4[j];
  }

  float hi = 0.0f, ci = 0.0f;
  for (int s = 0; s < LDN; ++s) {
    const float q = w20 * hi + w21 * ci;   // per-lane d; h,c lane-uniform
    float a0 = 0.f, a1 = 0.f, a2 = 0.f, a3 = 0.f;
    #pragma unroll
    for (int t = 0; t < LEN; ++t) {
      const float p = v * tanhf_(q + wcol[t]);
      const float4 m4 = *(const float4*)&M4L[w][t][0];   // uniform broadcast
      a0 += p * m4.x; a1 += p * m4.y; a2 += p * m4.z; a3 += p * m4.w;
    }
    #pragma unroll
    for (int off = 32; off >= 1; off >>= 1) {
      a0 += __shfl_xor(a0, off, 64);
      a1 += __shfl_xor(a1, off, 64);
      a2 += __shfl_xor(a2, off, 64);
      a3 += __shfl_xor(a3, off, 64);
    }
    const float g0 = a0 + cj[0] + whh4[0] * hi;
    const float g1 = a1 + cj[1] + whh4[1] * hi;
    const float g2 = a2 + cj[2] + whh4[2] * hi;
    const float g3 = a3 + cj[3] + whh4[3] * hi;
    ci = sigm(g1) * ci + sigm(g0) * tanhf_(g2);
    hi = sigm(g3) * tanhf_(ci);
    if (lane == 0) out[b * LDN + s] = hi;
  }
}

extern "C" void kernel_launch(void* const* d_in, const int* in_sizes, int n_in,
                              void* d_out, int out_size, void* d_ws, size_t ws_size,
                              hipStream_t stream) {
  (void)in_sizes; (void)n_in; (void)out_size;
  const float* ipq   = (const float*)d_in[0];
  const float* lblp  = (const float*)d_in[1];
  const float* e_h   = (const float*)d_in[2];
  const float* e_w   = (const float*)d_in[3];
  const float* e_m   = (const float*)d_in[4];
  const float* e_y   = (const float*)d_in[5];
  const float* Wi_w  = (const float*)d_in[6];
  const float* Wi_b  = (const float*)d_in[7];
  const float* We_w  = (const float*)d_in[8];
  const float* Vd_w  = (const float*)d_in[9];
  const float* Vd_b  = (const float*)d_in[10];
  const float* eWih  = (const float*)d_in[11];
  const float* eWhh  = (const float*)d_in[12];
  const float* ebih  = (const float*)d_in[13];
  const float* ebhh  = (const float*)d_in[14];
  const float* Wd_w  = (const float*)d_in[15];
  const float* Wd_b  = (const float*)d_in[16];
  const float* Wd2_w = (const float*)d_in[17];
  const float* Vdt_w = (const float*)d_in[18];
  const float* Vdt_b = (const float*)d_in[19];
  const float* dWih  = (const float*)d_in[20];
  const float* dWhh  = (const float*)d_in[21];
  const float* dbih  = (const float*)d_in[22];
  const float* dbhh  = (const float*)d_in[23];
  const int* itime   = (const int*)d_in[24];
  float* out = (float*)d_out;

  const size_t xpreB = (size_t)BB * LEN * XPS * 2;   // 167.77 MB
  const size_t wcvtB = (size_t)W_TOTAL * 2;          // 254 KB

  if (ws_size >= xpreB + wcvtB) {
    f16* xpre = (f16*)d_ws;
    f16* wcvt = (f16*)((char*)d_ws + xpreB);
    prep_all<<<dim3(PREP_BLOCKS + CONV_BLOCKS), dim3(256), 0, stream>>>(
        ipq, e_h, e_w, e_m, e_y, itime, xpre,
        Wi_w, We_w, Vd_w, eWih, eWhh, Wd_w, wcvt);
    enc_x<<<dim3(ENC_BLOCKS), dim3(512), 0, stream>>>(
        xpre, Wi_b, Vd_b, ebih, ebhh, Wd_b, wcvt, xpre);
    dec_kernel<<<dim3(DEC_BLOCKS), dim3(512), 0, stream>>>(
        xpre, xpre + 64, XPS, lblp, Wd2_w, Vdt_w, Vdt_b,
        dWih, dWhh, dbih, dbhh, out);
  } else {
    const size_t midB = (size_t)BB * LEN * HN * 2;   // 41.94 MB
    f16* mid  = (f16*)d_ws;
    f16* wmid = (f16*)((char*)d_ws + midB);
    f16* wcvt = (f16*)((char*)d_ws + 2 * midB);
    conv_w<<<dim3(CONV_BLOCKS), dim3(256), 0, stream>>>(
        Wi_w, We_w, Vd_w, eWih, eWhh, Wd_w, wcvt);
    enc_fb<<<dim3(ENC_BLOCKS), dim3(256), 0, stream>>>(
        ipq, e_h, e_w, e_m, e_y, Wi_b, Vd_b, ebih, ebhh, Wd_b, wcvt, itime,
        mid, wmid);
    dec_kernel<<<dim3(DEC_BLOCKS), dim3(512), 0, stream>>>(
        mid, wmid, HN, lblp, Wd2_w, Vdt_w, Vdt_b,
        dWih, dWhh, dbih, dbhh, out);
  }
}

// Round 7
// 794.217 us; speedup vs baseline: 1.1111x; 1.0102x over previous
//
#include <hip/hip_runtime.h>

#define BB   8192
#define LEN  40
#define LDN  12
#define PQN  237
#define INN  256
#define HN   64
#define BT   32                 // encoder batches per block (2 MFMA n-tiles)
#define ENC_BLOCKS (BB / BT)    // 256 -> 1 block/CU
#define DW   8                  // decoder batches per block (1 wave each)
#define DEC_BLOCKS (BB / DW)    // 1024
#define XPS  256                // xpre row stride in f16 (power of 2)

typedef unsigned int  u32;
typedef _Float16 f16;
typedef f16  half8 __attribute__((ext_vector_type(8)));
typedef f16  f16x4 __attribute__((ext_vector_type(4)));
typedef float f32x4 __attribute__((ext_vector_type(4)));

#define XS 264   // X/P LDS row stride (f16): reads 2-way max bank aliasing
#define HS 72    // U/H/C LDS row stride (f16): 2-way max

// weight offsets (f16 elements) in converted buffer
#define OFF_WI   0
#define OFF_WE   16384
#define OFF_VD   24576
#define OFF_WIH  40960
#define OFF_WHH  106496
#define OFF_WD   122880
#define W_TOTAL  126976

// LDS-staged embedding tables (f32) for fallback encoder
#define T_H   0
#define T_W   120
#define T_M   144
#define T_Y   196
#define T_TOT 574

#define PREP_BLOCKS (BB * LEN / 32)          // 10240
#define CONV_BLOCKS ((W_TOTAL + 255) / 256)  // 496

#define L2E   1.44269504f
#define L2E2  2.88539008f

__device__ __forceinline__ float rcp_(float x){
#if __has_builtin(__builtin_amdgcn_rcpf)
  return __builtin_amdgcn_rcpf(x);
#else
  return 1.0f / x;
#endif
}
// PRE-SCALED transcendentals: argument already multiplied by log2e (sigm)
// or 2*log2e (tanh) via weight/bias folding in conv.
__device__ __forceinline__ float sigm_pre(float x){
  return rcp_(1.0f + exp2f(-x));
}
__device__ __forceinline__ float tanh_pre(float x){
  return 1.0f - 2.0f * rcp_(exp2f(x) + 1.0f);
}
// full tanh for runtime (unscaled) arguments, e.g. tanh(c)
__device__ __forceinline__ float tanhf_(float x){
  float e = exp2f(L2E2 * x);
  return 1.0f - 2.0f * rcp_(e + 1.0f);
}

// lgkm-only barrier: LDS producer->consumer ordering WITHOUT draining vmcnt.
__device__ __forceinline__ void bar_lds(){
  asm volatile("s_waitcnt lgkmcnt(0)" ::: "memory");
  __builtin_amdgcn_s_barrier();
  asm volatile("" ::: "memory");
}

// scale folded into f16 weights: U path (Wi,We) x2log2e; Vd x log2e;
// Wih/Whh per-gate rows (g-gate x2log2e, i/f/o x log2e); Wd x2log2e (dec tanh)
__device__ __forceinline__ float wscale(int i){
  if      (i < OFF_WE)  return L2E2;                       // Wi
  else if (i < OFF_VD)  return L2E2;                       // We
  else if (i < OFF_WIH) return L2E;                        // Vd
  else if (i < OFF_WHH) {                                  // Wih rows
    const int r = (i - OFF_WIH) >> 8;                      // /256
    return ((r >> 6) == 2) ? L2E2 : L2E;
  }
  else if (i < OFF_WD) {                                   // Whh rows
    const int r = (i - OFF_WHH) >> 6;                      // /64
    return ((r >> 6) == 2) ? L2E2 : L2E;
  }
  else return L2E2;                                        // Wd
}

// ---------------- weight f32 -> f16 conversion (fallback path) -------------
__global__ __launch_bounds__(256) void conv_w(
    const float* __restrict__ Wi, const float* __restrict__ We,
    const float* __restrict__ Vd, const float* __restrict__ Wih,
    const float* __restrict__ Whh, const float* __restrict__ Wd,
    f16* __restrict__ dst)
{
  int i = blockIdx.x * 256 + threadIdx.x;
  if (i >= W_TOTAL) return;
  float v;
  if      (i < OFF_WE)  v = Wi [i - OFF_WI ];
  else if (i < OFF_VD)  v = We [i - OFF_WE ];
  else if (i < OFF_WIH) v = Vd [i - OFF_VD ];
  else if (i < OFF_WHH) v = Wih[i - OFF_WIH];
  else if (i < OFF_WD)  v = Whh[i - OFF_WHH];
  else                  v = Wd [i - OFF_WD ];
  dst[i] = (f16)(v * wscale(i));
}

// ---------------- prep_all: X materialization + fused weight convert -------
__global__ __launch_bounds__(256) void prep_all(
    const float* __restrict__ ipq,
    const float* __restrict__ e_h, const float* __restrict__ e_w,
    const float* __restrict__ e_m, const float* __restrict__ e_y,
    const int*  __restrict__ itime,
    f16* __restrict__ xpre,
    const float* __restrict__ Wi, const float* __restrict__ We,
    const float* __restrict__ Vd, const float* __restrict__ Wih,
    const float* __restrict__ Whh, const float* __restrict__ Wd,
    f16* __restrict__ wdst)
{
  if (blockIdx.x >= PREP_BLOCKS) {
    int i = (blockIdx.x - PREP_BLOCKS) * 256 + threadIdx.x;
    if (i >= W_TOTAL) return;
    float v;
    if      (i < OFF_WE)  v = Wi [i - OFF_WI ];
    else if (i < OFF_VD)  v = We [i - OFF_WE ];
    else if (i < OFF_WIH) v = Vd [i - OFF_VD ];
    else if (i < OFF_WHH) v = Whh ? Wih[i - OFF_WIH] : 0.f;
    else if (i < OFF_WD)  v = Whh[i - OFF_WHH];
    else                  v = Wd [i - OFF_WD ];
    if (i >= OFF_WIH && i < OFF_WHH) v = Wih[i - OFF_WIH];
    wdst[i] = (f16)(v * wscale(i));
    return;
  }
  const int wv = threadIdx.x >> 6, l = threadIdx.x & 63;
  const size_t row0 = (size_t)blockIdx.x * 32 + (size_t)wv * 8;
  int4 itv[8];
  #pragma unroll
  for (int r = 0; r < 8; ++r)
    itv[r] = *(const int4*)(itime + (row0 + r) * 4);
  #pragma unroll
  for (int r = 0; r < 8; ++r) {
    const size_t row = row0 + r;               // = b*LEN + t
    const float* src = ipq + row * PQN;
    f16* dst = xpre + row * XPS;
    #pragma unroll
    for (int k = 0; k < 3; ++k) {
      const int c = k * 64 + l;
      dst[c] = (f16)src[c];
    }
    {
      const int c = 192 + l;
      float v;
      if (c < PQN) v = src[c];
      else {
        const int o = c - PQN;
        if      (o < 5 ) v = e_h[itv[r].x * 5 + o];
        else if (o < 8 ) v = e_w[itv[r].y * 3 + (o - 5)];
        else if (o < 12) v = e_m[itv[r].z * 4 + (o - 8)];
        else             v = e_y[itv[r].w * 7 + (o - 12)];
      }
      dst[c] = (f16)v;
    }
  }
}

// ---------------- encoder v6: v5 structure + pre-scaled transcendentals ----
__global__ __launch_bounds__(512, 2) void enc_x(
    const f16* __restrict__ xpre,
    const float* __restrict__ Wi_b,   // (64)
    const float* __restrict__ Vd_b,   // (256)
    const float* __restrict__ ebih, const float* __restrict__ ebhh, // (256)
    const float* __restrict__ Wd_b,   // (64)
    const f16*  __restrict__ wAll,
    f16* __restrict__ xout)           // == xpre (overlay)
{
  __shared__ __attribute__((aligned(16))) f16 Xl[BT * XS];       // 16.9 KB
  __shared__ __attribute__((aligned(16))) f16 Ul[BT * HS];       //  4.6 KB
  __shared__ __attribute__((aligned(16))) f16 Hl[BT * HS];       //  4.6 KB
  __shared__ __attribute__((aligned(16))) f16 Cl[BT * HS];       //  4.6 KB
  __shared__ float Sred[2 * 64];                                 //  0.5 KB
  __shared__ __attribute__((aligned(16))) f16 WiL[4 * 8 * 64 * 8];  // 32 KB
  __shared__ __attribute__((aligned(16))) f16 WeL[4 * 4 * 64 * 8];  // 16 KB
  __shared__ __attribute__((aligned(16))) f16 VdL[16 * 2 * 64 * 8]; // 32 KB
  __shared__ __attribute__((aligned(16))) f16 WhL[16 * 2 * 64 * 8]; // 32 KB
  __shared__ __attribute__((aligned(16))) f16 WdL[4 * 2 * 64 * 8];  //  8 KB
  __shared__ float VdbL[256];
  __shared__ float EbsL[256];

  const int tid  = threadIdx.x;
  const int w    = tid >> 6;
  const int lane = tid & 63;
  const int nl   = lane & 15;
  const int q    = lane >> 4;
  const int wsub = w & 3;
  const int bt   = w >> 2;
  const int b0   = blockIdx.x * BT;
  const int d0   = wsub * 16 + q * 4;
  const int row  = bt * 16 + nl;     // batch row (n-dim) this wave's MFMA

  // staging map (512 thr): row r0(+16), 16B chunk off
  const int r0  = tid >> 5;          // 0..15
  const int off = tid & 31;
  const f16* gb0 = xpre + ((size_t)(b0 + r0     ) * LEN) * XPS + off * 8;
  const f16* gb1 = xpre + ((size_t)(b0 + r0 + 16) * LEN) * XPS + off * 8;
  const u32 lwa = (u32)(r0 * XS + off * 8);
  const u32 lwb = (u32)((r0 + 16) * XS + off * 8);

  // mid streaming map: one f16x4 per thread (32 rows x 64 cols)
  const int orow = tid >> 4;
  const int oc4  = (tid & 15) * 4;

  // ---- issue t=0 staging loads first ----
  half8 sr0 = *(const half8*)gb0;
  half8 sr1 = *(const half8*)gb1;

  // ---- register weights: Wih slices only (128 AGPR exactly) ----
  half8 whf[4][8];
  #pragma unroll
  for (int i = 0; i < 4; ++i) {
    const f16* ph = wAll + OFF_WIH + ((wsub + 4*i) * 16 + nl) * 256 + q * 8;
    #pragma unroll
    for (int kt = 0; kt < 8; ++kt) whf[i][kt] = *(const half8*)(ph + kt * 32);
  }
  float wib[4], wdb[4];
  #pragma unroll
  for (int r = 0; r < 4; ++r) {
    wib[r] = Wi_b[d0 + r] * L2E2;      // U pre-act scale
    wdb[r] = Wd_b[d0 + r] * L2E2;      // dec tanh path scale
  }

  // ---- LDS weights: [tile][kt][lane] fragment layout ----
  for (int s = tid; s < 4 * 8 * 64; s += 512) {     // Wi: 4 tiles, kt=8
    const int tile = s >> 9, kt = (s >> 6) & 7, ln = s & 63;
    *(half8*)(&WiL[(size_t)s * 8]) = *(const half8*)(
        wAll + OFF_WI + (tile * 16 + (ln & 15)) * 256 + (ln >> 4) * 8 + kt * 32);
  }
  for (int s = tid; s < 4 * 4 * 64; s += 512) {     // We: 4 tiles, j=4
    const int tile = s >> 8, j = (s >> 6) & 3, ln = s & 63;
    *(half8*)(&WeL[(size_t)s * 8]) = *(const half8*)(
        wAll + OFF_WE + (tile * 16 + (ln & 15)) * 128 + (ln >> 4) * 8 + j * 32);
  }
  for (int s = tid; s < 16 * 2 * 64; s += 512) {    // Vd: 16 tiles, kt=2
    const int tile = s >> 7, kt = (s >> 6) & 1, ln = s & 63;
    *(half8*)(&VdL[(size_t)s * 8]) = *(const half8*)(
        wAll + OFF_VD + (tile * 16 + (ln & 15)) * 64 + (ln >> 4) * 8 + kt * 32);
  }
  for (int s = tid; s < 16 * 2 * 64; s += 512) {    // Whh: 16 tiles, kt=2
    const int tile = s >> 7, kt = (s >> 6) & 1, ln = s & 63;
    *(half8*)(&WhL[(size_t)s * 8]) = *(const half8*)(
        wAll + OFF_WHH + (tile * 16 + (ln & 15)) * 64 + (ln >> 4) * 8 + kt * 32);
  }
  for (int s = tid; s < 4 * 2 * 64; s += 512) {     // Wd: 4 tiles, kt=2
    const int tile = s >> 7, kt = (s >> 6) & 1, ln = s & 63;
    *(half8*)(&WdL[(size_t)s * 8]) = *(const half8*)(
        wAll + OFF_WD + (tile * 16 + (ln & 15)) * 64 + (ln >> 4) * 8 + kt * 32);
  }
  if (tid < 256) {
    VdbL[tid] = Vd_b[tid] * L2E;
    EbsL[tid] = (ebih[tid] + ebhh[tid]) * (((tid >> 6) == 2) ? L2E2 : L2E);
  }
  for (int i = tid; i < BT * HS; i += 512) {
    Hl[i] = (f16)0.f; Cl[i] = (f16)0.f;
  }
  float creg[4] = {0.f, 0.f, 0.f, 0.f};
  bar_lds();

  for (int t = 0; t < LEN; ++t) {
    // ---- top: staged regs -> Xl; reissue prefetch for t+1 ----
    *(half8*)(&Xl[lwa]) = sr0;
    *(half8*)(&Xl[lwb]) = sr1;
    if (t + 1 < LEN) {
      sr0 = *(const half8*)(gb0 + (size_t)(t + 1) * XPS);
      sr1 = *(const half8*)(gb1 + (size_t)(t + 1) * XPS);
    }
    bar_lds();   // A: Xl ready; Hl/Cl(t-1) ready (written after D(t-1))

    // ---- phase 2: U = tanh(Wi@X + We@[H;C] + b); wm(t-1) direct store ----
    {
      f32x4 a0 = {0.f, 0.f, 0.f, 0.f}, a1 = {0.f, 0.f, 0.f, 0.f};
      const f16* xb = &Xl[row * XS + q * 8];
      #pragma unroll
      for (int kt = 0; kt < 4; ++kt)
        a0 = __builtin_amdgcn_mfma_f32_16x16x32_f16(
            *(const half8*)(&WiL[((wsub * 8 + kt) * 64 + lane) * 8]),
            *(const half8*)(xb + kt * 32), a0, 0, 0, 0);
      #pragma unroll
      for (int kt = 4; kt < 8; ++kt)
        a1 = __builtin_amdgcn_mfma_f32_16x16x32_f16(
            *(const half8*)(&WiL[((wsub * 8 + kt) * 64 + lane) * 8]),
            *(const half8*)(xb + kt * 32), a1, 0, 0, 0);
      const f16* hb = &Hl[row * HS + q * 8];
      const f16* cb = &Cl[row * HS + q * 8];
      half8 h0 = *(const half8*)hb, h1 = *(const half8*)(hb + 32);
      half8 c0 = *(const half8*)cb, c1 = *(const half8*)(cb + 32);
      a0 = __builtin_amdgcn_mfma_f32_16x16x32_f16(
          *(const half8*)(&WeL[((wsub * 4 + 0) * 64 + lane) * 8]), h0, a0, 0, 0, 0);
      a1 = __builtin_amdgcn_mfma_f32_16x16x32_f16(
          *(const half8*)(&WeL[((wsub * 4 + 1) * 64 + lane) * 8]), h1, a1, 0, 0, 0);
      a0 = __builtin_amdgcn_mfma_f32_16x16x32_f16(
          *(const half8*)(&WeL[((wsub * 4 + 2) * 64 + lane) * 8]), c0, a0, 0, 0, 0);
      a1 = __builtin_amdgcn_mfma_f32_16x16x32_f16(
          *(const half8*)(&WeL[((wsub * 4 + 3) * 64 + lane) * 8]), c1, a1, 0, 0, 0);
      f16x4 uv;
      #pragma unroll
      for (int r = 0; r < 4; ++r) uv[r] = (f16)tanh_pre(a0[r] + a1[r] + wib[r]);
      *(f16x4*)(&Ul[row * HS + d0]) = uv;
      if (t > 0) {   // wm(t-1): direct scattered 8B store
        f32x4 aw = {0.f, 0.f, 0.f, 0.f};
        aw = __builtin_amdgcn_mfma_f32_16x16x32_f16(
            *(const half8*)(&WdL[((wsub * 2 + 0) * 64 + lane) * 8]), h0, aw, 0, 0, 0);
        aw = __builtin_amdgcn_mfma_f32_16x16x32_f16(
            *(const half8*)(&WdL[((wsub * 2 + 1) * 64 + lane) * 8]), h1, aw, 0, 0, 0);
        f16x4 wv;
        #pragma unroll
        for (int r = 0; r < 4; ++r) wv[r] = (f16)(aw[r] + wdb[r]);
        *(f16x4*)(&xout[((size_t)(b0 + row) * LEN + (t - 1)) * XPS + 64 + d0]) = wv;
      }
    }
    bar_lds();   // B: Ul ready

    // ---- phase 3: stream mid(t-1); ee = exp2(Vd@U+b); P = X*ee ----
    if (t > 0) {
      f16x4 hv4 = *(const f16x4*)(&Hl[orow * HS + oc4]);
      *(f16x4*)(&xout[((size_t)(b0 + orow) * LEN + (t - 1)) * XPS + oc4]) = hv4;
    }
    {
      const f16* ub = &Ul[row * HS + q * 8];
      half8 u0 = *(const half8*)ub, u1 = *(const half8*)(ub + 32);
      float s = 0.f;
      #pragma unroll
      for (int i = 0; i < 4; ++i) {
        const int tile = wsub + 4 * i;
        f32x4 acc = {0.f, 0.f, 0.f, 0.f};
        acc = __builtin_amdgcn_mfma_f32_16x16x32_f16(
            *(const half8*)(&VdL[((tile * 2 + 0) * 64 + lane) * 8]), u0, acc, 0, 0, 0);
        acc = __builtin_amdgcn_mfma_f32_16x16x32_f16(
            *(const half8*)(&VdL[((tile * 2 + 1) * 64 + lane) * 8]), u1, acc, 0, 0, 0);
        const int k = tile * 16 + q * 4;
        f16x4 xv = *(const f16x4*)(&Xl[row * XS + k]);
        f16x4 pv;
        float ee[4];
        #pragma unroll
        for (int r = 0; r < 4; ++r) {
          ee[r] = exp2f(acc[r] + VdbL[k + r]);   // scale pre-folded
          s += ee[r];
          pv[r] = (f16)((float)xv[r] * ee[r]);
        }
        *(f16x4*)(&Xl[row * XS + k]) = pv;   // unnormalized P in place
      }
      s += __shfl_xor(s, 16, 64);
      s += __shfl_xor(s, 32, 64);
      if (lane < 16) Sred[bt * 64 + wsub * 16 + lane] = s;
    }
    bar_lds();   // C: P + Sred ready

    // ---- phase 4: gates; LSTM; stash; barrier D; H/C writes ----
    f16x4 hv, cv;
    {
      f32x4 g[4], gh[4];
      #pragma unroll
      for (int i = 0; i < 4; ++i) {
        g[i]  = (f32x4){0.f, 0.f, 0.f, 0.f};
        gh[i] = (f32x4){0.f, 0.f, 0.f, 0.f};
      }
      const f16* pb = &Xl[row * XS + q * 8];
      #pragma unroll
      for (int kt = 0; kt < 8; ++kt) {
        half8 bv = *(const half8*)(pb + kt * 32);
        #pragma unroll
        for (int i = 0; i < 4; ++i)
          g[i] = __builtin_amdgcn_mfma_f32_16x16x32_f16(whf[i][kt], bv, g[i], 0, 0, 0);
      }
      const f16* hb = &Hl[row * HS + q * 8];
      half8 h0 = *(const half8*)hb, h1 = *(const half8*)(hb + 32);
      #pragma unroll
      for (int i = 0; i < 4; ++i) {
        const int tile = wsub + 4 * i;
        gh[i] = __builtin_amdgcn_mfma_f32_16x16x32_f16(
            *(const half8*)(&WhL[((tile * 2 + 0) * 64 + lane) * 8]), h0, gh[i], 0, 0, 0);
        gh[i] = __builtin_amdgcn_mfma_f32_16x16x32_f16(
            *(const half8*)(&WhL[((tile * 2 + 1) * 64 + lane) * 8]), h1, gh[i], 0, 0, 0);
      }
      const float inv = rcp_(Sred[bt*64 + nl]      + Sred[bt*64 + 16 + nl]
                           + Sred[bt*64 + 32 + nl] + Sred[bt*64 + 48 + nl]);
      #pragma unroll
      for (int r = 0; r < 4; ++r) {
        const float gi = g[0][r] * inv + gh[0][r] + EbsL[0   + d0 + r];
        const float gf = g[1][r] * inv + gh[1][r] + EbsL[64  + d0 + r];
        const float gg = g[2][r] * inv + gh[2][r] + EbsL[128 + d0 + r];
        const float go = g[3][r] * inv + gh[3][r] + EbsL[192 + d0 + r];
        float c = sigm_pre(gf) * creg[r] + sigm_pre(gi) * tanh_pre(gg);
        creg[r] = c;
        const float h = sigm_pre(go) * tanhf_(c);
        hv[r] = (f16)h; cv[r] = (f16)c;
      }
    }
    bar_lds();   // D: all waves done reading P/H -> safe to overwrite H/C
    *(f16x4*)(&Hl[row * HS + d0]) = hv;
    *(f16x4*)(&Cl[row * HS + d0]) = cv;
  }

  // ---- epilogue: wm(LEN-1) + stream final mid (Hl = H_{LEN-1}) ----
  bar_lds();
  {
    const f16* hb = &Hl[row * HS + q * 8];
    half8 h0 = *(const half8*)hb, h1 = *(const half8*)(hb + 32);
    f32x4 aw = {0.f, 0.f, 0.f, 0.f};
    aw = __builtin_amdgcn_mfma_f32_16x16x32_f16(
        *(const half8*)(&WdL[((wsub * 2 + 0) * 64 + lane) * 8]), h0, aw, 0, 0, 0);
    aw = __builtin_amdgcn_mfma_f32_16x16x32_f16(
        *(const half8*)(&WdL[((wsub * 2 + 1) * 64 + lane) * 8]), h1, aw, 0, 0, 0);
    f16x4 wv;
    #pragma unroll
    for (int r = 0; r < 4; ++r) wv[r] = (f16)(aw[r] + wdb[r]);
    *(f16x4*)(&xout[((size_t)(b0 + row) * LEN + (LEN - 1)) * XPS + 64 + d0]) = wv;
    f16x4 hv4 = *(const f16x4*)(&Hl[orow * HS + oc4]);
    *(f16x4*)(&xout[((size_t)(b0 + orow) * LEN + (LEN - 1)) * XPS + oc4]) = hv4;
  }
}

// ---------------- fallback encoder (round-2 structure, scaled weights) -----
__global__ __launch_bounds__(256, 1) void enc_fb(
    const float* __restrict__ ipq,
    const float* __restrict__ e_h, const float* __restrict__ e_w,
    const float* __restrict__ e_m, const float* __restrict__ e_y,
    const float* __restrict__ Wi_b, const float* __restrict__ Vd_b,
    const float* __restrict__ ebih, const float* __restrict__ ebhh,
    const float* __restrict__ Wd_b, const f16* __restrict__ wAll,
    const int*  __restrict__ itime,
    f16* __restrict__ mid, f16* __restrict__ wmid)
{
  __shared__ __attribute__((aligned(16))) f16 Xl[BT * XS];
  __shared__ __attribute__((aligned(16))) f16 Ul[BT * HS];
  __shared__ __attribute__((aligned(16))) f16 Hl[BT * HS];
  __shared__ __attribute__((aligned(16))) f16 Cl[BT * HS];
  __shared__ float Sred[2 * 64];
  __shared__ float Tl[T_TOT];

  const int tid  = threadIdx.x;
  const int w    = tid >> 6;
  const int lane = tid & 63;
  const int nl   = lane & 15;
  const int q    = lane >> 4;
  const int b0   = blockIdx.x * BT;
  const int d0   = w * 16 + q * 4;

  const u32* pptr;
  int pstr, tstr, tbase = 0, twid = 0, tsub = 0;
  if (tid < PQN) {
    pptr = (const u32*)ipq + tid; pstr = LEN * PQN; tstr = PQN;
  } else {
    const int o = tid - PQN; int sel;
    if      (o < 5 ) { sel = 0; tbase = T_H; twid = 5; tsub = o;      }
    else if (o < 8 ) { sel = 1; tbase = T_W; twid = 3; tsub = o - 5;  }
    else if (o < 12) { sel = 2; tbase = T_M; twid = 4; tsub = o - 8;  }
    else             { sel = 3; tbase = T_Y; twid = 7; tsub = o - 12; }
    pptr = (const u32*)itime + sel; pstr = LEN * 4; tstr = 4;
  }
  pptr += (size_t)b0 * pstr;

  u32 pf[BT];
  #pragma unroll
  for (int bb = 0; bb < BT; ++bb) pf[bb] = pptr[(size_t)bb * pstr];

  half8 wif[8], wef[4], vdf[4][2], whf[4][8], whhf[4][2], wdf[2];
  {
    const f16* pw = wAll + OFF_WI + (w * 16 + nl) * 256 + q * 8;
    #pragma unroll
    for (int kt = 0; kt < 8; ++kt) wif[kt] = *(const half8*)(pw + kt * 32);
    const f16* pe = wAll + OFF_WE + (w * 16 + nl) * 128 + q * 8;
    #pragma unroll
    for (int kt = 0; kt < 4; ++kt) wef[kt] = *(const half8*)(pe + kt * 32);
    #pragma unroll
    for (int i = 0; i < 4; ++i) {
      const f16* pv = wAll + OFF_VD + ((w + 4*i) * 16 + nl) * 64 + q * 8;
      #pragma unroll
      for (int kt = 0; kt < 2; ++kt) vdf[i][kt] = *(const half8*)(pv + kt * 32);
      const f16* ph = wAll + OFF_WIH + ((w + 4*i) * 16 + nl) * 256 + q * 8;
      #pragma unroll
      for (int kt = 0; kt < 8; ++kt) whf[i][kt] = *(const half8*)(ph + kt * 32);
      const f16* pq = wAll + OFF_WHH + ((w + 4*i) * 16 + nl) * 64 + q * 8;
      #pragma unroll
      for (int kt = 0; kt < 2; ++kt) whhf[i][kt] = *(const half8*)(pq + kt * 32);
    }
    const f16* pd = wAll + OFF_WD + (w * 16 + nl) * 64 + q * 8;
    #pragma unroll
    for (int kt = 0; kt < 2; ++kt) wdf[kt] = *(const half8*)(pd + kt * 32);
  }

  float wib[4], vdb[16], ebs[16], wdb[4];
  #pragma unroll
  for (int r = 0; r < 4; ++r) {
    wib[r] = Wi_b[d0 + r] * L2E2;
    wdb[r] = Wd_b[d0 + r] * L2E2;
  }
  #pragma unroll
  for (int i = 0; i < 4; ++i)
    #pragma unroll
    for (int r = 0; r < 4; ++r) {
      vdb[i*4+r] = Vd_b[(w + 4*i) * 16 + q * 4 + r] * L2E;
      ebs[i*4+r] = (ebih[i * 64 + d0 + r] + ebhh[i * 64 + d0 + r])
                   * ((i == 2) ? L2E2 : L2E);
    }

  for (int i = tid; i < BT * HS; i += 256) { Hl[i] = (f16)0.f; Cl[i] = (f16)0.f; }
  for (int i = tid; i < T_TOT; i += 256) {
    float v;
    if      (i < T_W) v = e_h[i];
    else if (i < T_M) v = e_w[i - T_W];
    else if (i < T_Y) v = e_m[i - T_M];
    else              v = e_y[i - T_Y];
    Tl[i] = v;
  }
  float creg[2][4];
  #pragma unroll
  for (int bt = 0; bt < 2; ++bt)
    #pragma unroll
    for (int r = 0; r < 4; ++r) creg[bt][r] = 0.f;
  bar_lds();

  for (int t = 0; t < LEN; ++t) {
    #pragma unroll
    for (int bb = 0; bb < BT; ++bb) {
      float v;
      if (tid < PQN) v = __uint_as_float(pf[bb]);
      else           v = Tl[tbase + (int)pf[bb] * twid + tsub];
      Xl[bb * XS + tid] = (f16)v;
    }
    if (t + 1 < LEN) {
      const u32* pp = pptr + (size_t)(t + 1) * tstr;
      #pragma unroll
      for (int bb = 0; bb < BT; ++bb) pf[bb] = pp[(size_t)bb * pstr];
    }
    bar_lds();

    #pragma unroll
    for (int bt = 0; bt < 2; ++bt) {
      const int row = bt * 16 + nl;
      f32x4 acc = {0.f, 0.f, 0.f, 0.f};
      const f16* xb = &Xl[row * XS + q * 8];
      #pragma unroll
      for (int kt = 0; kt < 8; ++kt)
        acc = __builtin_amdgcn_mfma_f32_16x16x32_f16(wif[kt], *(const half8*)(xb + kt * 32), acc, 0, 0, 0);
      const f16* hb = &Hl[row * HS + q * 8];
      const f16* cb = &Cl[row * HS + q * 8];
      half8 h0 = *(const half8*)hb, h1 = *(const half8*)(hb + 32);
      half8 c0 = *(const half8*)cb, c1 = *(const half8*)(cb + 32);
      acc = __builtin_amdgcn_mfma_f32_16x16x32_f16(wef[0], h0, acc, 0, 0, 0);
      acc = __builtin_amdgcn_mfma_f32_16x16x32_f16(wef[1], h1, acc, 0, 0, 0);
      acc = __builtin_amdgcn_mfma_f32_16x16x32_f16(wef[2], c0, acc, 0, 0, 0);
      acc = __builtin_amdgcn_mfma_f32_16x16x32_f16(wef[3], c1, acc, 0, 0, 0);
      f16x4 uv;
      #pragma unroll
      for (int r = 0; r < 4; ++r) uv[r] = (f16)tanh_pre(acc[r] + wib[r]);
      *(f16x4*)(&Ul[row * HS + d0]) = uv;
      if (t > 0) {
        f32x4 aw = {0.f, 0.f, 0.f, 0.f};
        aw = __builtin_amdgcn_mfma_f32_16x16x32_f16(wdf[0], h0, aw, 0, 0, 0);
        aw = __builtin_amdgcn_mfma_f32_16x16x32_f16(wdf[1], h1, aw, 0, 0, 0);
        f16x4 wv;
        #pragma unroll
        for (int r = 0; r < 4; ++r) wv[r] = (f16)(aw[r] + wdb[r]);
        *(f16x4*)(&wmid[((size_t)(b0 + row) * LEN + (t - 1)) * HN + d0]) = wv;
      }
    }
    bar_lds();

    #pragma unroll
    for (int bt = 0; bt < 2; ++bt) {
      const int row = bt * 16 + nl;
      const f16* ub = &Ul[row * HS + q * 8];
      half8 u0 = *(const half8*)ub, u1 = *(const half8*)(ub + 32);
      float ee[16];
      #pragma unroll
      for (int i = 0; i < 4; ++i) {
        f32x4 acc = {0.f, 0.f, 0.f, 0.f};
        acc = __builtin_amdgcn_mfma_f32_16x16x32_f16(vdf[i][0], u0, acc, 0, 0, 0);
        acc = __builtin_amdgcn_mfma_f32_16x16x32_f16(vdf[i][1], u1, acc, 0, 0, 0);
        #pragma unroll
        for (int r = 0; r < 4; ++r)
          ee[i*4+r] = exp2f(acc[r] + vdb[i*4+r]);
      }
      float s = 0.f;
      #pragma unroll
      for (int j = 0; j < 16; ++j) s += ee[j];
      s += __shfl_xor(s, 16, 64);
      s += __shfl_xor(s, 32, 64);
      if (lane < 16) Sred[bt * 64 + w * 16 + lane] = s;
      #pragma unroll
      for (int i = 0; i < 4; ++i) {
        const int k = (w + 4*i) * 16 + q * 4;
        f16x4 xv = *(const f16x4*)(&Xl[row * XS + k]);
        f16x4 pv;
        #pragma unroll
        for (int r = 0; r < 4; ++r) pv[r] = (f16)((float)xv[r] * ee[i*4+r]);
        *(f16x4*)(&Xl[row * XS + k]) = pv;
      }
    }
    bar_lds();

    f16x4 hstash[2], cstash[2];
    #pragma unroll
    for (int bt = 0; bt < 2; ++bt) {
      const int row = bt * 16 + nl;
      f32x4 g[4], gh[4];
      #pragma unroll
      for (int i = 0; i < 4; ++i) {
        g[i]  = (f32x4){0.f, 0.f, 0.f, 0.f};
        gh[i] = (f32x4){0.f, 0.f, 0.f, 0.f};
      }
      const f16* pb = &Xl[row * XS + q * 8];
      #pragma unroll
      for (int kt = 0; kt < 8; ++kt) {
        half8 bv = *(const half8*)(pb + kt * 32);
        #pragma unroll
        for (int i = 0; i < 4; ++i)
          g[i] = __builtin_amdgcn_mfma_f32_16x16x32_f16(whf[i][kt], bv, g[i], 0, 0, 0);
      }
      const f16* hb = &Hl[row * HS + q * 8];
      half8 h0 = *(const half8*)hb, h1 = *(const half8*)(hb + 32);
      #pragma unroll
      for (int i = 0; i < 4; ++i) {
        gh[i] = __builtin_amdgcn_mfma_f32_16x16x32_f16(whhf[i][0], h0, gh[i], 0, 0, 0);
        gh[i] = __builtin_amdgcn_mfma_f32_16x16x32_f16(whhf[i][1], h1, gh[i], 0, 0, 0);
      }
      const float inv = rcp_(Sred[bt*64 + nl]      + Sred[bt*64 + 16 + nl]
                           + Sred[bt*64 + 32 + nl] + Sred[bt*64 + 48 + nl]);
      f16x4 hv, cv;
      #pragma unroll
      for (int r = 0; r < 4; ++r) {
        const float gi = g[0][r] * inv + gh[0][r] + ebs[0  + r];
        const float gf = g[1][r] * inv + gh[1][r] + ebs[4  + r];
        const float gg = g[2][r] * inv + gh[2][r] + ebs[8  + r];
        const float go = g[3][r] * inv + gh[3][r] + ebs[12 + r];
        float c = sigm_pre(gf) * creg[bt][r] + sigm_pre(gi) * tanh_pre(gg);
        creg[bt][r] = c;
        const float h = sigm_pre(go) * tanhf_(c);
        hv[r] = (f16)h; cv[r] = (f16)c;
      }
      hstash[bt] = hv; cstash[bt] = cv;
      *(f16x4*)(&mid[((size_t)(b0 + row) * LEN + t) * HN + d0]) = hv;
    }
    bar_lds();
    #pragma unroll
    for (int bt = 0; bt < 2; ++bt) {
      const int row = bt * 16 + nl;
      *(f16x4*)(&Hl[row * HS + d0]) = hstash[bt];
      *(f16x4*)(&Cl[row * HS + d0]) = cstash[bt];
    }
  }

  bar_lds();
  #pragma unroll
  for (int bt = 0; bt < 2; ++bt) {
    const int row = bt * 16 + nl;
    const f16* hb = &Hl[row * HS + q * 8];
    half8 h0 = *(const half8*)hb, h1 = *(const half8*)(hb + 32);
    f32x4 aw = {0.f, 0.f, 0.f, 0.f};
    aw = __builtin_amdgcn_mfma_f32_16x16x32_f16(wdf[0], h0, aw, 0, 0, 0);
    aw = __builtin_amdgcn_mfma_f32_16x16x32_f16(wdf[1], h1, aw, 0, 0, 0);
    f16x4 wv;
    #pragma unroll
    for (int r = 0; r < 4; ++r) wv[r] = (f16)(aw[r] + wdb[r]);
    *(f16x4*)(&wmid[((size_t)(b0 + row) * LEN + (LEN - 1)) * HN + d0]) = wv;
  }
}

// ---------------- decoder v5: lane = d, pre-scaled transcendentals ---------
// wm arrives pre-scaled by 2*log2e (Wd folded); Wd2 scaled at load; ws4/M4
// scaled per-gate so gates are in exp2 domain -> no muls in hot loop.
__global__ __launch_bounds__(512) void dec_kernel(
    const f16* __restrict__ mids,     // cols 0..63 at stride MS per (b,t)
    const f16* __restrict__ wms,      // cols 0..63 at stride MS per (b,t)
    const int MS,
    const float* __restrict__ lblp,
    const float* __restrict__ Wd2_w,  // (64,2)
    const float* __restrict__ Vdt_w,  // (1,64)
    const float* __restrict__ Vdt_b,  // (1)
    const float* __restrict__ dWih,   // (4,65)
    const float* __restrict__ dWhh,   // (4,1)
    const float* __restrict__ dbih, const float* __restrict__ dbhh,
    float* __restrict__ out)          // (B,LD)
{
  __shared__ __attribute__((aligned(16))) float M4L[DW][LEN][4];  // 5.1 KB
  __shared__ __attribute__((aligned(16))) float ws4[4 * 65];

  const int w    = threadIdx.x >> 6;
  const int lane = threadIdx.x & 63;
  const int b    = blockIdx.x * DW + w;

  // wm column d=lane over all t -> f32 registers (pre-scaled by 2log2e)
  float wcol[LEN];
  #pragma unroll
  for (int t = 0; t < LEN; ++t)
    wcol[t] = (float)wms[((size_t)b * LEN + t) * MS + lane];

  // ws4 scaled per-gate: j=2 (g) -> 2log2e, else log2e
  if (threadIdx.x < 4 * 65) {
    const int j = threadIdx.x / 65;
    ws4[threadIdx.x] = dWih[threadIdx.x] * ((j == 2) ? L2E2 : L2E);
  }
  __syncthreads();   // ws4 visible to all waves

  // M4 precompute: lane = t (40 active); macc carries the gate scale
  float macc[4] = {0.f, 0.f, 0.f, 0.f};
  if (lane < LEN) {
    const f16* mrow = mids + ((size_t)b * LEN + lane) * MS;
    #pragma unroll
    for (int k8 = 0; k8 < 8; ++k8) {
      half8 mv = *(const half8*)(mrow + k8 * 8);
      #pragma unroll
      for (int e = 0; e < 8; ++e) {
        const float m = (float)mv[e];
        #pragma unroll
        for (int j = 0; j < 4; ++j) macc[j] += ws4[j * 65 + k8 * 8 + e] * m;
      }
    }
  }
  float sm4[4];
  #pragma unroll
  for (int j = 0; j < 4; ++j) {
    float p = macc[j];
    #pragma unroll
    for (int off = 32; off >= 1; off >>= 1) p += __shfl_xor(p, off, 64);
    sm4[j] = p;
  }
  if (lane < LEN) {
    M4L[w][lane][0] = macc[0]; M4L[w][lane][1] = macc[1];
    M4L[w][lane][2] = macc[2]; M4L[w][lane][3] = macc[3];
  }

  const float dpin = lblp[b * LEN + (LEN - 1)];
  const float w20  = Wd2_w[2 * lane]     * L2E2;   // tanh arg pre-scale
  const float w21  = Wd2_w[2 * lane + 1] * L2E2;
  const float v    = Vdt_w[lane];
  const float vdtb = Vdt_b[0];
  float cj[4], whh4[4];
  #pragma unroll
  for (int j = 0; j < 4; ++j) {
    const float sj = (j == 2) ? L2E2 : L2E;
    whh4[j] = dWhh[j] * sj;
    cj[j] = sj * (dWih[j * 65 + 64] * dpin + dbih[j] + dbhh[j])
          + vdtb * sm4[j];                      // sm4 already carries sj
  }

  float hi = 0.0f, ci = 0.0f;
  for (int s = 0; s < LDN; ++s) {
    const float q = w20 * hi + w21 * ci;   // per-lane d; h,c lane-uniform
    float a0 = 0.f, a1 = 0.f, a2 = 0.f, a3 = 0.f;
    #pragma unroll
    for (int t = 0; t < LEN; ++t) {
      const float p = v * tanh_pre(q + wcol[t]);   // no mul: pre-scaled
      const float4 m4 = *(const float4*)&M4L[w][t][0];
      a0 += p * m4.x; a1 += p * m4.y; a2 += p * m4.z; a3 += p * m4.w;
    }
    #pragma unroll
    for (int off = 32; off >= 1; off >>= 1) {
      a0 += __shfl_xor(a0, off, 64);
      a1 += __shfl_xor(a1, off, 64);
      a2 += __shfl_xor(a2, off, 64);
      a3 += __shfl_xor(a3, off, 64);
    }
    const float g0 = a0 + cj[0] + whh4[0] * hi;
    const float g1 = a1 + cj[1] + whh4[1] * hi;
    const float g2 = a2 + cj[2] + whh4[2] * hi;
    const float g3 = a3 + cj[3] + whh4[3] * hi;
    ci = sigm_pre(g1) * ci + sigm_pre(g0) * tanh_pre(g2);
    hi = sigm_pre(g3) * tanhf_(ci);
    if (lane == 0) out[b * LDN + s] = hi;
  }
}

extern "C" void kernel_launch(void* const* d_in, const int* in_sizes, int n_in,
                              void* d_out, int out_size, void* d_ws, size_t ws_size,
                              hipStream_t stream) {
  (void)in_sizes; (void)n_in; (void)out_size;
  const float* ipq   = (const float*)d_in[0];
  const float* lblp  = (const float*)d_in[1];
  const float* e_h   = (const float*)d_in[2];
  const float* e_w   = (const float*)d_in[3];
  const float* e_m   = (const float*)d_in[4];
  const float* e_y   = (const float*)d_in[5];
  const float* Wi_w  = (const float*)d_in[6];
  const float* Wi_b  = (const float*)d_in[7];
  const float* We_w  = (const float*)d_in[8];
  const float* Vd_w  = (const float*)d_in[9];
  const float* Vd_b  = (const float*)d_in[10];
  const float* eWih  = (const float*)d_in[11];
  const float* eWhh  = (const float*)d_in[12];
  const float* ebih  = (const float*)d_in[13];
  const float* ebhh  = (const float*)d_in[14];
  const float* Wd_w  = (const float*)d_in[15];
  const float* Wd_b  = (const float*)d_in[16];
  const float* Wd2_w = (const float*)d_in[17];
  const float* Vdt_w = (const float*)d_in[18];
  const float* Vdt_b = (const float*)d_in[19];
  const float* dWih  = (const float*)d_in[20];
  const float* dWhh  = (const float*)d_in[21];
  const float* dbih  = (const float*)d_in[22];
  const float* dbhh  = (const float*)d_in[23];
  const int* itime   = (const int*)d_in[24];
  float* out = (float*)d_out;

  const size_t xpreB = (size_t)BB * LEN * XPS * 2;   // 167.77 MB
  const size_t wcvtB = (size_t)W_TOTAL * 2;          // 254 KB

  if (ws_size >= xpreB + wcvtB) {
    f16* xpre = (f16*)d_ws;
    f16* wcvt = (f16*)((char*)d_ws + xpreB);
    prep_all<<<dim3(PREP_BLOCKS + CONV_BLOCKS), dim3(256), 0, stream>>>(
        ipq, e_h, e_w, e_m, e_y, itime, xpre,
        Wi_w, We_w, Vd_w, eWih, eWhh, Wd_w, wcvt);
    enc_x<<<dim3(ENC_BLOCKS), dim3(512), 0, stream>>>(
        xpre, Wi_b, Vd_b, ebih, ebhh, Wd_b, wcvt, xpre);
    dec_kernel<<<dim3(DEC_BLOCKS), dim3(512), 0, stream>>>(
        xpre, xpre + 64, XPS, lblp, Wd2_w, Vdt_w, Vdt_b,
        dWih, dWhh, dbih, dbhh, out);
  } else {
    const size_t midB = (size_t)BB * LEN * HN * 2;   // 41.94 MB
    f16* mid  = (f16*)d_ws;
    f16* wmid = (f16*)((char*)d_ws + midB);
    f16* wcvt = (f16*)((char*)d_ws + 2 * midB);
    conv_w<<<dim3(CONV_BLOCKS), dim3(256), 0, stream>>>(
        Wi_w, We_w, Vd_w, eWih, eWhh, Wd_w, wcvt);
    enc_fb<<<dim3(ENC_BLOCKS), dim3(256), 0, stream>>>(
        ipq, e_h, e_w, e_m, e_y, Wi_b, Vd_b, ebih, ebhh, Wd_b, wcvt, itime,
        mid, wmid);
    dec_kernel<<<dim3(DEC_BLOCKS), dim3(512), 0, stream>>>(
        mid, wmid, HN, lblp, Wd2_w, Vdt_w, Vdt_b,
        dWih, dWhh, dbih, dbhh, out);
  }
}